// Round 3
// baseline (161.292 us; speedup 1.0000x reference)
//
#include <hip/hip_runtime.h>
#include <hip/hip_fp16.h>

#define B_ 4
#define T_ 4096
#define D_ 1024

typedef _Float16 h8 __attribute__((ext_vector_type(8)));
typedef _Float16 h4 __attribute__((ext_vector_type(4)));
typedef float f32x4 __attribute__((ext_vector_type(4)));

#define LOG2E 1.44269504088896340736f
#define MASKV -3.0e38f
#define MINIT -1.0e30f
#define EXP2(x) __builtin_amdgcn_exp2f(x)

// ---------------- kernel 0: W (1024x192 f32) -> Wt (192x1024 f16), LDS transpose
__global__ __launch_bounds__(256) void wt_kernel(const float* __restrict__ W,
                                                 _Float16* __restrict__ Wt) {
    __shared__ _Float16 Tr[192][20];
    const int tid = threadIdx.x, k0 = blockIdx.x * 16;   // grid 64
#pragma unroll
    for (int i = 0; i < 3; i++) {
        int fi = tid + 256 * i;                 // 768 float4 = 16 rows x 48
        int r = fi / 48, c4 = fi % 48;
        float4 v = *(const float4*)(W + (size_t)(k0 + r) * 192 + c4 * 4);
        Tr[c4 * 4 + 0][r] = (_Float16)v.x;
        Tr[c4 * 4 + 1][r] = (_Float16)v.y;
        Tr[c4 * 4 + 2][r] = (_Float16)v.z;
        Tr[c4 * 4 + 3][r] = (_Float16)v.w;
    }
    __syncthreads();
#pragma unroll
    for (int i = 0; i < 3; i++) {
        int oi = tid + 256 * i;                 // 768 h4 = 192 rows x 4
        int n = oi >> 2, kq = oi & 3;
        *(h4*)(Wt + (size_t)n * D_ + k0 + kq * 4) = *(const h4*)&Tr[n][kq * 4];
    }
}

// ---------------- kernel 1: qkv projection, BM=32 BN=192 BK=32, dbuf LDS, grid 512
// Ost epilogue staging overlaid on As/Bs -> 35.8 KB LDS -> 4 blocks/CU.
// T14: prefetch issued AFTER the barrier so the compiler's vmcnt(0)-before-s_barrier
// drain only covers already-consumed loads; next-tile loads overlap the MFMA phase.
__global__ __launch_bounds__(256) void proj_kernel(
    const float* __restrict__ x, const _Float16* __restrict__ Wt,
    const float* __restrict__ bias,
    _Float16* __restrict__ qh, _Float16* __restrict__ kh, _Float16* __restrict__ vh)
{
    __shared__ __align__(16) char psm[35840];
    _Float16* Asp = (_Float16*)psm;             // [2][32][40]
    _Float16* Bsp = (_Float16*)(psm + 5120);    // [2][192][40]
    _Float16* Ostp = (_Float16*)psm;            // [32][200] (aliases As/Bs, used after)
    const int tid = threadIdx.x;
    const int w = tid >> 6, lane = tid & 63, quad = lane >> 4, l16 = lane & 15;
    const int row0 = blockIdx.x * 32;
    const int mstrip = w & 1;
    const int ngrp = (w >> 1) * 6;

    float bvals[6];
#pragma unroll
    for (int nt = 0; nt < 6; nt++) bvals[nt] = bias[(ngrp + nt) * 16 + l16];

    f32x4 acc[6];
#pragma unroll
    for (int i = 0; i < 6; i++) acc[i] = (f32x4){0.f, 0.f, 0.f, 0.f};

    const int arow = tid >> 3, ac0 = (tid & 7) * 4;

    float4 xa;
    h8 wreg[3];
    {
        xa = *(const float4*)(x + (size_t)(row0 + arow) * D_ + ac0);
#pragma unroll
        for (int p = 0; p < 3; p++) {
            int f = tid + 256 * p; int n = f >> 2, c0 = (f & 3) * 8;
            wreg[p] = *(const h8*)(Wt + (size_t)n * D_ + c0);
        }
    }

    for (int kc = 0; kc < 32; kc++) {
        const int buf = kc & 1;
        h4 av;
        av[0]=(_Float16)xa.x; av[1]=(_Float16)xa.y; av[2]=(_Float16)xa.z; av[3]=(_Float16)xa.w;
        *(h4*)(Asp + buf * 1280 + arow * 40 + ac0) = av;
#pragma unroll
        for (int p = 0; p < 3; p++) {
            int f = tid + 256 * p; int n = f >> 2, c0 = (f & 3) * 8;
            *(h8*)(Bsp + buf * 7680 + n * 40 + c0) = wreg[p];
        }
        __syncthreads();
        if (kc + 1 < 32) {   // prefetch AFTER barrier: loads fly under the MFMA phase
            int k0 = (kc + 1) * 32;
            xa = *(const float4*)(x + (size_t)(row0 + arow) * D_ + k0 + ac0);
#pragma unroll
            for (int p = 0; p < 3; p++) {
                int f = tid + 256 * p; int n = f >> 2, c0 = (f & 3) * 8;
                wreg[p] = *(const h8*)(Wt + (size_t)n * D_ + k0 + c0);
            }
        }
        h8 a0 = *(const h8*)(Asp + buf * 1280 + (16 * mstrip + l16) * 40 + quad * 8);
#pragma unroll
        for (int nt = 0; nt < 6; nt++) {
            h8 b0 = *(const h8*)(Bsp + buf * 7680 + ((ngrp + nt) * 16 + l16) * 40 + quad * 8);
            acc[nt] = __builtin_amdgcn_mfma_f32_16x16x32_f16(a0, b0, acc[nt], 0, 0, 0);
        }
    }

    __syncthreads();   // all waves done with As/Bs before Ost overlay
#pragma unroll
    for (int nt = 0; nt < 6; nt++) {
        int n = (ngrp + nt) * 16 + l16;
        float scale = (n < 64) ? LOG2E : 1.0f;   // q pre-scaled for exp2 softmax
#pragma unroll
        for (int reg = 0; reg < 4; reg++)
            Ostp[(16 * mstrip + quad * 4 + reg) * 200 + n] =
                (_Float16)((acc[nt][reg] + bvals[nt]) * scale);
    }
    __syncthreads();
    {
        const int mrow = tid >> 3, c0 = (tid & 7) * 8;
        _Float16* dsts[3] = {qh, kh, vh};
#pragma unroll
        for (int g = 0; g < 3; g++)
            *(h8*)(dsts[g] + (size_t)(row0 + mrow) * 64 + c0) =
                *(const h8*)(Ostp + mrow * 200 + g * 64 + c0);
    }
}

// ---------------- kernel 2: flash attention chunks; 128-row q-tile (2 strips/wave),
// K+V dbuf in LDS, transposed-S, XCD-clustered. launch_bounds(256,2): no VGPR spill.
// T14: K/V prefetch for kt+1 issued AFTER the barrier (see proj_kernel note) —
// global latency hides under QK^T/softmax/PV instead of stalling the barrier drain.
__global__ __launch_bounds__(256, 2) void attn_kernel(
    const _Float16* __restrict__ qh, const _Float16* __restrict__ kh,
    const _Float16* __restrict__ vh, float* __restrict__ out,
    _Float16* __restrict__ Opart, float2* __restrict__ ml,
    int lgC, int NC1, int direct, int q8, int total)
{
    __shared__ _Float16 Ks[2][64][72];   // [buf][s][d]; reused as 128x72 O-staging
    __shared__ _Float16 Vt[2][64][72];   // [buf][p][s]
    const int tid = threadIdx.x;
    const int w = tid >> 6, lane = tid & 63, quad = lane >> 4, l16 = lane & 15;
    const int C = 1 << lgC;

    const int bid = blockIdx.x;
    const int cid = (bid & 7) * q8 + (bid >> 3);   // XCD clustering
    if (cid >= total) return;

    const int b = cid / NC1;
    int rem = cid - b * NC1;
    int qt2 = 0, k0 = 0, cnt = 1;
    for (int i = 0; i < 32; i++) {
        int nc = (2 * i + 2 + C - 1) >> lgC;
        if (rem < nc) { qt2 = i; k0 = rem << lgC; cnt = min(C, 2 * i + 2 - k0); break; }
        rem -= nc;
    }
    const size_t base = (size_t)b * T_ * 64;
    const int qbase = qt2 * 128 + w * 32;   // wave's first q-row

    // Q fragments for 2 strips (A/B layout: [l16][quad*8+j])
    h8 qf[2][2];
#pragma unroll
    for (int u = 0; u < 2; u++) {
        const _Float16* qp = qh + base + (size_t)(qbase + u * 16 + l16) * 64 + quad * 8;
        qf[u][0] = *(const h8*)qp;
        qf[u][1] = *(const h8*)(qp + 32);
    }

    f32x4 o[8];   // O^T tiles, C-layout: row=p(quad*4+reg), col=m(l16)
#pragma unroll
    for (int i = 0; i < 8; i++) o[i] = (f32x4){0.f, 0.f, 0.f, 0.f};
    float m[2] = {MINIT, MINIT}, l[2] = {0.f, 0.f};

    // staging maps
    const int krow = tid >> 3, kc0 = (tid & 7) * 8;          // K: 2 x h8 per thread
    const int vp0 = (tid & 15) * 4, vc0 = (tid >> 4) * 4;    // V: 4 x h4, reg transpose
    h8 kreg[2];
    h4 vreg[4];
    {
        const _Float16* kp = kh + base + (size_t)(k0 * 64) * 64;
        kreg[0] = *(const h8*)(kp + (size_t)krow * 64 + kc0);
        kreg[1] = *(const h8*)(kp + (size_t)(krow + 32) * 64 + kc0);
        const _Float16* vp = vh + base + (size_t)(k0 * 64 + vc0) * 64 + vp0;
#pragma unroll
        for (int i = 0; i < 4; i++) vreg[i] = *(const h4*)(vp + (size_t)i * 64);
    }

    const int kend = k0 + cnt;
    for (int kt = k0; kt < kend; kt++) {
        const int buf = kt & 1;
        *(h8*)&Ks[buf][krow][kc0] = kreg[0];
        *(h8*)&Ks[buf][krow + 32][kc0] = kreg[1];
#pragma unroll
        for (int j = 0; j < 4; j++) {
            h4 t;
            t[0] = vreg[0][j]; t[1] = vreg[1][j]; t[2] = vreg[2][j]; t[3] = vreg[3][j];
            *(h4*)&Vt[buf][vp0 + j][vc0] = t;
        }
        __syncthreads();
        if (kt + 1 < kend) {   // prefetch AFTER barrier: overlaps compute below
            const _Float16* kp = kh + base + (size_t)((kt + 1) * 64) * 64;
            kreg[0] = *(const h8*)(kp + (size_t)krow * 64 + kc0);
            kreg[1] = *(const h8*)(kp + (size_t)(krow + 32) * 64 + kc0);
            const _Float16* vp = vh + base + (size_t)((kt + 1) * 64 + vc0) * 64 + vp0;
#pragma unroll
            for (int i = 0; i < 4; i++) vreg[i] = *(const h4*)(vp + (size_t)i * 64);
        }

        const bool skip = (kt * 64) > (qbase + 31);   // wave fully above diagonal
        if (!skip) {
            // S^T = K Q^T : D[s=quad*4+reg][m=l16], per strip u; kf shared across strips
            f32x4 s[2][4];
#pragma unroll
            for (int nt = 0; nt < 4; nt++) {
                h8 kf0 = *(const h8*)&Ks[buf][nt * 16 + l16][quad * 8];
                h8 kf1 = *(const h8*)&Ks[buf][nt * 16 + l16][32 + quad * 8];
#pragma unroll
                for (int u = 0; u < 2; u++) {
                    f32x4 c = (f32x4){0.f, 0.f, 0.f, 0.f};
                    c = __builtin_amdgcn_mfma_f32_16x16x32_f16(kf0, qf[u][0], c, 0, 0, 0);
                    c = __builtin_amdgcn_mfma_f32_16x16x32_f16(kf1, qf[u][1], c, 0, 0, 0);
                    s[u][nt] = c;
                }
            }

            h4 pf[2][4];
#pragma unroll
            for (int u = 0; u < 2; u++) {
                const int qrow = qbase + u * 16 + l16;
                if (kt * 64 + 63 > qbase + u * 16) {   // causal mask needed
#pragma unroll
                    for (int nt = 0; nt < 4; nt++)
#pragma unroll
                        for (int reg = 0; reg < 4; reg++) {
                            int sg = kt * 64 + nt * 16 + quad * 4 + reg;
                            if (sg > qrow) s[u][nt][reg] = MASKV;
                        }
                }
                float mx = s[u][0][0];
#pragma unroll
                for (int nt = 0; nt < 4; nt++)
#pragma unroll
                    for (int reg = 0; reg < 4; reg++) mx = fmaxf(mx, s[u][nt][reg]);
                mx = fmaxf(mx, __shfl_xor(mx, 16));
                mx = fmaxf(mx, __shfl_xor(mx, 32));
                float mnew = fmaxf(m[u], mx);
                float alpha = EXP2(m[u] - mnew);
                m[u] = mnew;
                float rs = 0.f;
#pragma unroll
                for (int nt = 0; nt < 4; nt++) {
                    h4 ph;
#pragma unroll
                    for (int reg = 0; reg < 4; reg++) {
                        float p = EXP2(s[u][nt][reg] - mnew);
                        rs += p;
                        ph[reg] = (_Float16)p;
                    }
                    pf[u][nt] = ph;
                }
                rs += __shfl_xor(rs, 16);
                rs += __shfl_xor(rs, 32);
                l[u] = l[u] * alpha + rs;
#pragma unroll
                for (int pt = 0; pt < 4; pt++)
#pragma unroll
                    for (int reg = 0; reg < 4; reg++) o[u * 4 + pt][reg] *= alpha;
            }

            // O^T += V^T P^T ; vf shared across strips
#pragma unroll
            for (int pt = 0; pt < 4; pt++)
#pragma unroll
                for (int nt = 0; nt < 4; nt++) {
                    h4 vf = *(const h4*)&Vt[buf][pt * 16 + l16][nt * 16 + quad * 4];
                    o[pt]     = __builtin_amdgcn_mfma_f32_16x16x16f16(vf, pf[0][nt], o[pt], 0, 0, 0);
                    o[4 + pt] = __builtin_amdgcn_mfma_f32_16x16x16f16(vf, pf[1][nt], o[4 + pt], 0, 0, 0);
                }
        }
    }

    if (direct) {
#pragma unroll
        for (int u = 0; u < 2; u++) {
            float linv = 1.0f / l[u];
            int trow = qt2 * 128 + w * 32 + u * 16 + l16;
#pragma unroll
            for (int pt = 0; pt < 4; pt++)
#pragma unroll
                for (int reg = 0; reg < 4; reg++)
                    out[base + (size_t)trow * 64 + pt * 16 + quad * 4 + reg] =
                        o[u * 4 + pt][reg] * linv;
        }
    } else {
        // stage O^T -> LDS -> coalesced h8 stores
        __syncthreads();                       // all waves done reading Ks/Vt
        _Float16* St = &Ks[0][0][0];           // 128 x 72 halfs (exactly 9216)
#pragma unroll
        for (int u = 0; u < 2; u++) {
            int r = w * 32 + u * 16 + l16;
#pragma unroll
            for (int pt = 0; pt < 4; pt++) {
                h4 ph;
#pragma unroll
                for (int reg = 0; reg < 4; reg++) ph[reg] = (_Float16)o[u * 4 + pt][reg];
                *(h4*)&St[r * 72 + pt * 16 + quad * 4] = ph;
            }
            if (quad == 0) ml[(size_t)cid * 128 + r] = make_float2(m[u], l[u]);
        }
        __syncthreads();
        _Float16* op = Opart + (size_t)cid * 8192;   // [128][64] f16
        const int r = tid >> 1, c0 = (tid & 1) * 32;
#pragma unroll
        for (int j = 0; j < 4; j++)
            *(h8*)(op + r * 64 + c0 + 8 * j) = *(const h8*)&St[r * 72 + c0 + 8 * j];
    }
}

// ---------------- kernel 3: merge split-K partials; grid 1024 (16-row groups)
__global__ __launch_bounds__(256) void combine_kernel(
    const _Float16* __restrict__ Opart, const float2* __restrict__ ml,
    float* __restrict__ out, int lgC, int NC1)
{
    const int C = 1 << lgC;
    const int task = blockIdx.x;                  // b(2b) | tile(5b) | rg(3b)
    const int b = task >> 8, tile = (task >> 3) & 31, rg = task & 7;
    int pref = 0;
    for (int i = 0; i < tile; i++) pref += (2 * i + 2 + C - 1) >> lgC;
    const int cbase = b * NC1 + pref;
    const int nch = (2 * tile + 2 + C - 1) >> lgC;

    const int r = rg * 16 + (threadIdx.x >> 4);   // local row in [0,128)
    const int c0 = (threadIdx.x & 15) * 4;

    float M = MINIT;
    for (int i = 0; i < nch; i++) M = fmaxf(M, ml[(size_t)(cbase + i) * 128 + r].x);
    float L = 0.f, acc[4] = {0.f, 0.f, 0.f, 0.f};
    for (int i = 0; i < nch; i++) {
        float2 v = ml[(size_t)(cbase + i) * 128 + r];
        float sc = EXP2(v.x - M);
        L += sc * v.y;
        h4 x4 = *(const h4*)(Opart + (size_t)(cbase + i) * 8192 + (size_t)r * 64 + c0);
#pragma unroll
        for (int t = 0; t < 4; t++) acc[t] += sc * (float)x4[t];
    }
    float inv = 1.0f / L;
    float4 res = { acc[0]*inv, acc[1]*inv, acc[2]*inv, acc[3]*inv };
    *(float4*)(out + ((size_t)b * T_ + tile * 128 + r) * 64 + c0) = res;
}

extern "C" void kernel_launch(void* const* d_in, const int* in_sizes, int n_in,
                              void* d_out, int out_size, void* d_ws, size_t ws_size,
                              hipStream_t stream) {
    const float* x    = (const float*)d_in[0];
    const float* W    = (const float*)d_in[1];
    const float* bias = (const float*)d_in[2];
    float* out = (float*)d_out;
    char* ws = (char*)d_ws;
    _Float16* qh = (_Float16*)(ws);
    _Float16* kh = (_Float16*)(ws + (size_t)2 * 1024 * 1024);
    _Float16* vh = (_Float16*)(ws + (size_t)4 * 1024 * 1024);
    _Float16* Wt = (_Float16*)(ws + (size_t)6 * 1024 * 1024);
    const size_t pbase = (size_t)8 * 1024 * 1024;

    // smallest C whose f16 partials fit in ws (128-row tiles)
    int lgC = -1, nc1 = 32;
    for (int lg = 2; lg <= 6; lg++) {
        int C = 1 << lg, n1 = 0;
        for (int i = 0; i < 32; i++) n1 += (2 * i + 2 + C - 1) >> lg;
        size_t need = pbase + (size_t)4 * n1 * (8192 * 2 + 128 * 8);
        if (need <= ws_size) { lgC = lg; nc1 = n1; break; }
    }
    int direct = (lgC < 0) ? 1 : 0;
    if (direct) { lgC = 6; nc1 = 32; }
    _Float16* Opart = (_Float16*)(ws + pbase);
    float2*   mlp   = (float2*)(ws + pbase + (size_t)4 * nc1 * 8192 * 2);

    const int total = 4 * nc1;
    const int q8 = (total + 7) / 8;

    wt_kernel<<<64, 256, 0, stream>>>(W, Wt);
    proj_kernel<<<512, 256, 0, stream>>>(x, Wt, bias, qh, kh, vh);
    attn_kernel<<<8 * q8, 256, 0, stream>>>(qh, kh, vh, out, Opart, mlp,
                                            lgC, nc1, direct, q8, total);
    if (!direct)
        combine_kernel<<<1024, 256, 0, stream>>>(Opart, mlp, out, lgC, nc1);
}

// Round 4
// 146.342 us; speedup vs baseline: 1.1022x; 1.1022x over previous
//
#include <hip/hip_runtime.h>
#include <hip/hip_fp16.h>

#define B_ 4
#define T_ 4096
#define D_ 1024

typedef _Float16 h8 __attribute__((ext_vector_type(8)));
typedef _Float16 h4 __attribute__((ext_vector_type(4)));
typedef float f32x4 __attribute__((ext_vector_type(4)));

#define LOG2E 1.44269504088896340736f
#define MASKV -3.0e38f
#define MINIT -1.0e30f
#define EXP2(x) __builtin_amdgcn_exp2f(x)

// ---------------- kernel 0: W (1024x192 f32) -> Wt (192x1024 f16), LDS transpose
__global__ __launch_bounds__(256) void wt_kernel(const float* __restrict__ W,
                                                 _Float16* __restrict__ Wt) {
    __shared__ _Float16 Tr[192][20];
    const int tid = threadIdx.x, k0 = blockIdx.x * 16;   // grid 64
#pragma unroll
    for (int i = 0; i < 3; i++) {
        int fi = tid + 256 * i;                 // 768 float4 = 16 rows x 48
        int r = fi / 48, c4 = fi % 48;
        float4 v = *(const float4*)(W + (size_t)(k0 + r) * 192 + c4 * 4);
        Tr[c4 * 4 + 0][r] = (_Float16)v.x;
        Tr[c4 * 4 + 1][r] = (_Float16)v.y;
        Tr[c4 * 4 + 2][r] = (_Float16)v.z;
        Tr[c4 * 4 + 3][r] = (_Float16)v.w;
    }
    __syncthreads();
#pragma unroll
    for (int i = 0; i < 3; i++) {
        int oi = tid + 256 * i;                 // 768 h4 = 192 rows x 4
        int n = oi >> 2, kq = oi & 3;
        *(h4*)(Wt + (size_t)n * D_ + k0 + kq * 4) = *(const h4*)&Tr[n][kq * 4];
    }
}

// ---------------- kernel 1: qkv projection, BM=32 BN=192, BK=128 (8 chunks),
// single-buffer LDS (A[32][136] + B[192][136] = 60.9 KB -> 2 blocks/CU), chunk-deep
// register prefetch issued after the stage barrier: loads get the whole ~700-cycle
// compute phase to land instead of one thin 32-K iteration (42.5us was latency-bound:
// MfmaUtil 4.9%, HBM 12%, 3190 cyc/iter). 24 MFMA/wave per barrier pair.
__global__ __launch_bounds__(256, 2) void proj_kernel(
    const float* __restrict__ x, const _Float16* __restrict__ Wt,
    const float* __restrict__ bias,
    _Float16* __restrict__ qh, _Float16* __restrict__ kh, _Float16* __restrict__ vh)
{
    __shared__ __align__(16) char psm[60928];
    _Float16* Asp = (_Float16*)psm;             // [32][136]
    _Float16* Bsp = (_Float16*)(psm + 8704);    // [192][136]
    _Float16* Ostp = (_Float16*)psm;            // [32][200] epilogue overlay
    const int tid = threadIdx.x;
    const int w = tid >> 6, lane = tid & 63, quad = lane >> 4, l16 = lane & 15;
    const int row0 = blockIdx.x * 32;
    const int mstrip = w & 1;
    const int ngrp = (w >> 1) * 6;

    float bvals[6];
#pragma unroll
    for (int nt = 0; nt < 6; nt++) bvals[nt] = bias[(ngrp + nt) * 16 + l16];

    f32x4 acc[6];
#pragma unroll
    for (int i = 0; i < 6; i++) acc[i] = (f32x4){0.f, 0.f, 0.f, 0.f};

    // staging maps: A: 4 float4/thread (32 rows x 128 cols f32)
    //               B: 12 h8/thread  (192 rows x 128 cols f16)
    const int arow = tid >> 3, ac = (tid & 7) * 4;
    const float* xrow = x + (size_t)(row0 + arow) * D_;

    float4 xa[4];
    h8 wreg[12];
    // prologue: chunk 0 loads
#pragma unroll
    for (int p = 0; p < 4; p++) xa[p] = *(const float4*)(xrow + p * 32 + ac);
#pragma unroll
    for (int p = 0; p < 12; p++) {
        int f = tid + 256 * p; int n = f >> 4, c = (f & 15) * 8;
        wreg[p] = *(const h8*)(Wt + (size_t)n * D_ + c);
    }

    for (int it = 0; it < 8; it++) {
        if (it) __syncthreads();           // all waves done reading previous chunk
        // stage regs -> LDS
#pragma unroll
        for (int p = 0; p < 4; p++) {
            h4 av;
            av[0] = (_Float16)xa[p].x; av[1] = (_Float16)xa[p].y;
            av[2] = (_Float16)xa[p].z; av[3] = (_Float16)xa[p].w;
            *(h4*)(Asp + arow * 136 + p * 32 + ac) = av;
        }
#pragma unroll
        for (int p = 0; p < 12; p++) {
            int f = tid + 256 * p; int n = f >> 4, c = (f & 15) * 8;
            *(h8*)(Bsp + n * 136 + c) = wreg[p];
        }
        __syncthreads();
        if (it + 1 < 8) {                  // prefetch next chunk; lands during compute
            const int k0 = (it + 1) * 128;
#pragma unroll
            for (int p = 0; p < 4; p++) xa[p] = *(const float4*)(xrow + k0 + p * 32 + ac);
#pragma unroll
            for (int p = 0; p < 12; p++) {
                int f = tid + 256 * p; int n = f >> 4, c = (f & 15) * 8;
                wreg[p] = *(const h8*)(Wt + (size_t)n * D_ + k0 + c);
            }
        }
        // compute: 4 K-slices of 32, 6 N-tiles each
#pragma unroll
        for (int kk = 0; kk < 4; kk++) {
            h8 a0 = *(const h8*)(Asp + (16 * mstrip + l16) * 136 + kk * 32 + quad * 8);
#pragma unroll
            for (int nt = 0; nt < 6; nt++) {
                h8 b0 = *(const h8*)(Bsp + ((ngrp + nt) * 16 + l16) * 136 + kk * 32 + quad * 8);
                acc[nt] = __builtin_amdgcn_mfma_f32_16x16x32_f16(a0, b0, acc[nt], 0, 0, 0);
            }
        }
    }

    __syncthreads();   // all waves done with As/Bs before Ost overlay
#pragma unroll
    for (int nt = 0; nt < 6; nt++) {
        int n = (ngrp + nt) * 16 + l16;
        float scale = (n < 64) ? LOG2E : 1.0f;   // q pre-scaled for exp2 softmax
#pragma unroll
        for (int reg = 0; reg < 4; reg++)
            Ostp[(16 * mstrip + quad * 4 + reg) * 200 + n] =
                (_Float16)((acc[nt][reg] + bvals[nt]) * scale);
    }
    __syncthreads();
    {
        const int mrow = tid >> 3, c0 = (tid & 7) * 8;
        _Float16* dsts[3] = {qh, kh, vh};
#pragma unroll
        for (int g = 0; g < 3; g++)
            *(h8*)(dsts[g] + (size_t)(row0 + mrow) * 64 + c0) =
                *(const h8*)(Ostp + mrow * 200 + g * 64 + c0);
    }
}

// ---------------- kernel 2: flash attention chunks; 128-row q-tile (2 strips/wave),
// K+V dbuf in LDS, transposed-S, XCD-clustered. launch_bounds(256,2): no VGPR spill.
// (R2-verified form: prefetch issued before the barrier.)
__global__ __launch_bounds__(256, 2) void attn_kernel(
    const _Float16* __restrict__ qh, const _Float16* __restrict__ kh,
    const _Float16* __restrict__ vh, float* __restrict__ out,
    _Float16* __restrict__ Opart, float2* __restrict__ ml,
    int lgC, int NC1, int direct, int q8, int total)
{
    __shared__ _Float16 Ks[2][64][72];   // [buf][s][d]; reused as 128x72 O-staging
    __shared__ _Float16 Vt[2][64][72];   // [buf][p][s]
    const int tid = threadIdx.x;
    const int w = tid >> 6, lane = tid & 63, quad = lane >> 4, l16 = lane & 15;
    const int C = 1 << lgC;

    const int bid = blockIdx.x;
    const int cid = (bid & 7) * q8 + (bid >> 3);   // XCD clustering
    if (cid >= total) return;

    const int b = cid / NC1;
    int rem = cid - b * NC1;
    int qt2 = 0, k0 = 0, cnt = 1;
    for (int i = 0; i < 32; i++) {
        int nc = (2 * i + 2 + C - 1) >> lgC;
        if (rem < nc) { qt2 = i; k0 = rem << lgC; cnt = min(C, 2 * i + 2 - k0); break; }
        rem -= nc;
    }
    const size_t base = (size_t)b * T_ * 64;
    const int qbase = qt2 * 128 + w * 32;   // wave's first q-row

    // Q fragments for 2 strips (A/B layout: [l16][quad*8+j])
    h8 qf[2][2];
#pragma unroll
    for (int u = 0; u < 2; u++) {
        const _Float16* qp = qh + base + (size_t)(qbase + u * 16 + l16) * 64 + quad * 8;
        qf[u][0] = *(const h8*)qp;
        qf[u][1] = *(const h8*)(qp + 32);
    }

    f32x4 o[8];   // O^T tiles, C-layout: row=p(quad*4+reg), col=m(l16)
#pragma unroll
    for (int i = 0; i < 8; i++) o[i] = (f32x4){0.f, 0.f, 0.f, 0.f};
    float m[2] = {MINIT, MINIT}, l[2] = {0.f, 0.f};

    // staging maps
    const int krow = tid >> 3, kc0 = (tid & 7) * 8;          // K: 2 x h8 per thread
    const int vp0 = (tid & 15) * 4, vc0 = (tid >> 4) * 4;    // V: 4 x h4, reg transpose
    h8 kreg[2];
    h4 vreg[4];
    {
        const _Float16* kp = kh + base + (size_t)(k0 * 64) * 64;
        kreg[0] = *(const h8*)(kp + (size_t)krow * 64 + kc0);
        kreg[1] = *(const h8*)(kp + (size_t)(krow + 32) * 64 + kc0);
        const _Float16* vp = vh + base + (size_t)(k0 * 64 + vc0) * 64 + vp0;
#pragma unroll
        for (int i = 0; i < 4; i++) vreg[i] = *(const h4*)(vp + (size_t)i * 64);
    }

    const int kend = k0 + cnt;
    for (int kt = k0; kt < kend; kt++) {
        const int buf = kt & 1;
        *(h8*)&Ks[buf][krow][kc0] = kreg[0];
        *(h8*)&Ks[buf][krow + 32][kc0] = kreg[1];
#pragma unroll
        for (int j = 0; j < 4; j++) {
            h4 t;
            t[0] = vreg[0][j]; t[1] = vreg[1][j]; t[2] = vreg[2][j]; t[3] = vreg[3][j];
            *(h4*)&Vt[buf][vp0 + j][vc0] = t;
        }
        if (kt + 1 < kend) {   // prefetch next K/V tiles into regs
            const _Float16* kp = kh + base + (size_t)((kt + 1) * 64) * 64;
            kreg[0] = *(const h8*)(kp + (size_t)krow * 64 + kc0);
            kreg[1] = *(const h8*)(kp + (size_t)(krow + 32) * 64 + kc0);
            const _Float16* vp = vh + base + (size_t)((kt + 1) * 64 + vc0) * 64 + vp0;
#pragma unroll
            for (int i = 0; i < 4; i++) vreg[i] = *(const h4*)(vp + (size_t)i * 64);
        }
        __syncthreads();

        const bool skip = (kt * 64) > (qbase + 31);   // wave fully above diagonal
        if (!skip) {
            // S^T = K Q^T : D[s=quad*4+reg][m=l16], per strip u; kf shared across strips
            f32x4 s[2][4];
#pragma unroll
            for (int nt = 0; nt < 4; nt++) {
                h8 kf0 = *(const h8*)&Ks[buf][nt * 16 + l16][quad * 8];
                h8 kf1 = *(const h8*)&Ks[buf][nt * 16 + l16][32 + quad * 8];
#pragma unroll
                for (int u = 0; u < 2; u++) {
                    f32x4 c = (f32x4){0.f, 0.f, 0.f, 0.f};
                    c = __builtin_amdgcn_mfma_f32_16x16x32_f16(kf0, qf[u][0], c, 0, 0, 0);
                    c = __builtin_amdgcn_mfma_f32_16x16x32_f16(kf1, qf[u][1], c, 0, 0, 0);
                    s[u][nt] = c;
                }
            }

            h4 pf[2][4];
#pragma unroll
            for (int u = 0; u < 2; u++) {
                const int qrow = qbase + u * 16 + l16;
                if (kt * 64 + 63 > qbase + u * 16) {   // causal mask needed
#pragma unroll
                    for (int nt = 0; nt < 4; nt++)
#pragma unroll
                        for (int reg = 0; reg < 4; reg++) {
                            int sg = kt * 64 + nt * 16 + quad * 4 + reg;
                            if (sg > qrow) s[u][nt][reg] = MASKV;
                        }
                }
                float mx = s[u][0][0];
#pragma unroll
                for (int nt = 0; nt < 4; nt++)
#pragma unroll
                    for (int reg = 0; reg < 4; reg++) mx = fmaxf(mx, s[u][nt][reg]);
                mx = fmaxf(mx, __shfl_xor(mx, 16));
                mx = fmaxf(mx, __shfl_xor(mx, 32));
                float mnew = fmaxf(m[u], mx);
                float alpha = EXP2(m[u] - mnew);
                m[u] = mnew;
                float rs = 0.f;
#pragma unroll
                for (int nt = 0; nt < 4; nt++) {
                    h4 ph;
#pragma unroll
                    for (int reg = 0; reg < 4; reg++) {
                        float p = EXP2(s[u][nt][reg] - mnew);
                        rs += p;
                        ph[reg] = (_Float16)p;
                    }
                    pf[u][nt] = ph;
                }
                rs += __shfl_xor(rs, 16);
                rs += __shfl_xor(rs, 32);
                l[u] = l[u] * alpha + rs;
#pragma unroll
                for (int pt = 0; pt < 4; pt++)
#pragma unroll
                    for (int reg = 0; reg < 4; reg++) o[u * 4 + pt][reg] *= alpha;
            }

            // O^T += V^T P^T ; vf shared across strips
#pragma unroll
            for (int pt = 0; pt < 4; pt++)
#pragma unroll
                for (int nt = 0; nt < 4; nt++) {
                    h4 vf = *(const h4*)&Vt[buf][pt * 16 + l16][nt * 16 + quad * 4];
                    o[pt]     = __builtin_amdgcn_mfma_f32_16x16x16f16(vf, pf[0][nt], o[pt], 0, 0, 0);
                    o[4 + pt] = __builtin_amdgcn_mfma_f32_16x16x16f16(vf, pf[1][nt], o[4 + pt], 0, 0, 0);
                }
        }
    }

    if (direct) {
#pragma unroll
        for (int u = 0; u < 2; u++) {
            float linv = 1.0f / l[u];
            int trow = qt2 * 128 + w * 32 + u * 16 + l16;
#pragma unroll
            for (int pt = 0; pt < 4; pt++)
#pragma unroll
                for (int reg = 0; reg < 4; reg++)
                    out[base + (size_t)trow * 64 + pt * 16 + quad * 4 + reg] =
                        o[u * 4 + pt][reg] * linv;
        }
    } else {
        // stage O^T -> LDS -> coalesced h8 stores
        __syncthreads();                       // all waves done reading Ks/Vt
        _Float16* St = &Ks[0][0][0];           // 128 x 72 halfs (exactly 9216)
#pragma unroll
        for (int u = 0; u < 2; u++) {
            int r = w * 32 + u * 16 + l16;
#pragma unroll
            for (int pt = 0; pt < 4; pt++) {
                h4 ph;
#pragma unroll
                for (int reg = 0; reg < 4; reg++) ph[reg] = (_Float16)o[u * 4 + pt][reg];
                *(h4*)&St[r * 72 + pt * 16 + quad * 4] = ph;
            }
            if (quad == 0) ml[(size_t)cid * 128 + r] = make_float2(m[u], l[u]);
        }
        __syncthreads();
        _Float16* op = Opart + (size_t)cid * 8192;   // [128][64] f16
        const int r = tid >> 1, c0 = (tid & 1) * 32;
#pragma unroll
        for (int j = 0; j < 4; j++)
            *(h8*)(op + r * 64 + c0 + 8 * j) = *(const h8*)&St[r * 72 + c0 + 8 * j];
    }
}

// ---------------- kernel 3: merge split-K partials; grid 1024 (16-row groups)
__global__ __launch_bounds__(256) void combine_kernel(
    const _Float16* __restrict__ Opart, const float2* __restrict__ ml,
    float* __restrict__ out, int lgC, int NC1)
{
    const int C = 1 << lgC;
    const int task = blockIdx.x;                  // b(2b) | tile(5b) | rg(3b)
    const int b = task >> 8, tile = (task >> 3) & 31, rg = task & 7;
    int pref = 0;
    for (int i = 0; i < tile; i++) pref += (2 * i + 2 + C - 1) >> lgC;
    const int cbase = b * NC1 + pref;
    const int nch = (2 * tile + 2 + C - 1) >> lgC;

    const int r = rg * 16 + (threadIdx.x >> 4);   // local row in [0,128)
    const int c0 = (threadIdx.x & 15) * 4;

    float M = MINIT;
    for (int i = 0; i < nch; i++) M = fmaxf(M, ml[(size_t)(cbase + i) * 128 + r].x);
    float L = 0.f, acc[4] = {0.f, 0.f, 0.f, 0.f};
    for (int i = 0; i < nch; i++) {
        float2 v = ml[(size_t)(cbase + i) * 128 + r];
        float sc = EXP2(v.x - M);
        L += sc * v.y;
        h4 x4 = *(const h4*)(Opart + (size_t)(cbase + i) * 8192 + (size_t)r * 64 + c0);
#pragma unroll
        for (int t = 0; t < 4; t++) acc[t] += sc * (float)x4[t];
    }
    float inv = 1.0f / L;
    float4 res = { acc[0]*inv, acc[1]*inv, acc[2]*inv, acc[3]*inv };
    *(float4*)(out + ((size_t)b * T_ + tile * 128 + r) * 64 + c0) = res;
}

extern "C" void kernel_launch(void* const* d_in, const int* in_sizes, int n_in,
                              void* d_out, int out_size, void* d_ws, size_t ws_size,
                              hipStream_t stream) {
    const float* x    = (const float*)d_in[0];
    const float* W    = (const float*)d_in[1];
    const float* bias = (const float*)d_in[2];
    float* out = (float*)d_out;
    char* ws = (char*)d_ws;
    _Float16* qh = (_Float16*)(ws);
    _Float16* kh = (_Float16*)(ws + (size_t)2 * 1024 * 1024);
    _Float16* vh = (_Float16*)(ws + (size_t)4 * 1024 * 1024);
    _Float16* Wt = (_Float16*)(ws + (size_t)6 * 1024 * 1024);
    const size_t pbase = (size_t)8 * 1024 * 1024;

    // smallest C whose f16 partials fit in ws (128-row tiles)
    int lgC = -1, nc1 = 32;
    for (int lg = 2; lg <= 6; lg++) {
        int C = 1 << lg, n1 = 0;
        for (int i = 0; i < 32; i++) n1 += (2 * i + 2 + C - 1) >> lg;
        size_t need = pbase + (size_t)4 * n1 * (8192 * 2 + 128 * 8);
        if (need <= ws_size) { lgC = lg; nc1 = n1; break; }
    }
    int direct = (lgC < 0) ? 1 : 0;
    if (direct) { lgC = 6; nc1 = 32; }
    _Float16* Opart = (_Float16*)(ws + pbase);
    float2*   mlp   = (float2*)(ws + pbase + (size_t)4 * nc1 * 8192 * 2);

    const int total = 4 * nc1;
    const int q8 = (total + 7) / 8;

    wt_kernel<<<64, 256, 0, stream>>>(W, Wt);
    proj_kernel<<<512, 256, 0, stream>>>(x, Wt, bias, qh, kh, vh);
    attn_kernel<<<8 * q8, 256, 0, stream>>>(qh, kh, vh, out, Opart, mlp,
                                            lgC, nc1, direct, q8, total);
    if (!direct)
        combine_kernel<<<1024, 256, 0, stream>>>(Opart, mlp, out, lgC, nc1);
}

// Round 5
// 145.678 us; speedup vs baseline: 1.1072x; 1.0046x over previous
//
#include <hip/hip_runtime.h>
#include <hip/hip_fp16.h>

#define B_ 4
#define T_ 4096
#define D_ 1024

typedef _Float16 h8 __attribute__((ext_vector_type(8)));
typedef _Float16 h4 __attribute__((ext_vector_type(4)));
typedef float f32x4 __attribute__((ext_vector_type(4)));

#define LOG2E 1.44269504088896340736f
#define MASKV -3.0e38f
#define MINIT -1.0e30f
#define EXP2(x) __builtin_amdgcn_exp2f(x)

// ---------------- kernel 0: W (1024x192 f32) -> Wt (192x1024 f16), LDS transpose
__global__ __launch_bounds__(256) void wt_kernel(const float* __restrict__ W,
                                                 _Float16* __restrict__ Wt) {
    __shared__ _Float16 Tr[192][20];
    const int tid = threadIdx.x, k0 = blockIdx.x * 16;   // grid 64
#pragma unroll
    for (int i = 0; i < 3; i++) {
        int fi = tid + 256 * i;                 // 768 float4 = 16 rows x 48
        int r = fi / 48, c4 = fi % 48;
        float4 v = *(const float4*)(W + (size_t)(k0 + r) * 192 + c4 * 4);
        Tr[c4 * 4 + 0][r] = (_Float16)v.x;
        Tr[c4 * 4 + 1][r] = (_Float16)v.y;
        Tr[c4 * 4 + 2][r] = (_Float16)v.z;
        Tr[c4 * 4 + 3][r] = (_Float16)v.w;
    }
    __syncthreads();
#pragma unroll
    for (int i = 0; i < 3; i++) {
        int oi = tid + 256 * i;                 // 768 h4 = 192 rows x 4
        int n = oi >> 2, kq = oi & 3;
        *(h4*)(Wt + (size_t)n * D_ + k0 + kq * 4) = *(const h4*)&Tr[n][kq * 4];
    }
}

// ---------------- kernel 1: qkv projection, BM=32 BN=192, BK=128 (8 chunks),
// single-buffer LDS (A[32][136] + B[192][136] = 60.9 KB -> 2 blocks/CU), chunk-deep
// register prefetch issued after the stage barrier (R4-verified: proj ~42.5 -> ~17us).
__global__ __launch_bounds__(256, 2) void proj_kernel(
    const float* __restrict__ x, const _Float16* __restrict__ Wt,
    const float* __restrict__ bias,
    _Float16* __restrict__ qh, _Float16* __restrict__ kh, _Float16* __restrict__ vh)
{
    __shared__ __align__(16) char psm[60928];
    _Float16* Asp = (_Float16*)psm;             // [32][136]
    _Float16* Bsp = (_Float16*)(psm + 8704);    // [192][136]
    _Float16* Ostp = (_Float16*)psm;            // [32][200] epilogue overlay
    const int tid = threadIdx.x;
    const int w = tid >> 6, lane = tid & 63, quad = lane >> 4, l16 = lane & 15;
    const int row0 = blockIdx.x * 32;
    const int mstrip = w & 1;
    const int ngrp = (w >> 1) * 6;

    float bvals[6];
#pragma unroll
    for (int nt = 0; nt < 6; nt++) bvals[nt] = bias[(ngrp + nt) * 16 + l16];

    f32x4 acc[6];
#pragma unroll
    for (int i = 0; i < 6; i++) acc[i] = (f32x4){0.f, 0.f, 0.f, 0.f};

    // staging maps: A: 4 float4/thread (32 rows x 128 cols f32)
    //               B: 12 h8/thread  (192 rows x 128 cols f16)
    const int arow = tid >> 3, ac = (tid & 7) * 4;
    const float* xrow = x + (size_t)(row0 + arow) * D_;

    float4 xa[4];
    h8 wreg[12];
    // prologue: chunk 0 loads
#pragma unroll
    for (int p = 0; p < 4; p++) xa[p] = *(const float4*)(xrow + p * 32 + ac);
#pragma unroll
    for (int p = 0; p < 12; p++) {
        int f = tid + 256 * p; int n = f >> 4, c = (f & 15) * 8;
        wreg[p] = *(const h8*)(Wt + (size_t)n * D_ + c);
    }

    for (int it = 0; it < 8; it++) {
        if (it) __syncthreads();           // all waves done reading previous chunk
        // stage regs -> LDS
#pragma unroll
        for (int p = 0; p < 4; p++) {
            h4 av;
            av[0] = (_Float16)xa[p].x; av[1] = (_Float16)xa[p].y;
            av[2] = (_Float16)xa[p].z; av[3] = (_Float16)xa[p].w;
            *(h4*)(Asp + arow * 136 + p * 32 + ac) = av;
        }
#pragma unroll
        for (int p = 0; p < 12; p++) {
            int f = tid + 256 * p; int n = f >> 4, c = (f & 15) * 8;
            *(h8*)(Bsp + n * 136 + c) = wreg[p];
        }
        __syncthreads();
        if (it + 1 < 8) {                  // prefetch next chunk; lands during compute
            const int k0 = (it + 1) * 128;
#pragma unroll
            for (int p = 0; p < 4; p++) xa[p] = *(const float4*)(xrow + k0 + p * 32 + ac);
#pragma unroll
            for (int p = 0; p < 12; p++) {
                int f = tid + 256 * p; int n = f >> 4, c = (f & 15) * 8;
                wreg[p] = *(const h8*)(Wt + (size_t)n * D_ + k0 + c);
            }
        }
        // compute: 4 K-slices of 32, 6 N-tiles each
#pragma unroll
        for (int kk = 0; kk < 4; kk++) {
            h8 a0 = *(const h8*)(Asp + (16 * mstrip + l16) * 136 + kk * 32 + quad * 8);
#pragma unroll
            for (int nt = 0; nt < 6; nt++) {
                h8 b0 = *(const h8*)(Bsp + ((ngrp + nt) * 16 + l16) * 136 + kk * 32 + quad * 8);
                acc[nt] = __builtin_amdgcn_mfma_f32_16x16x32_f16(a0, b0, acc[nt], 0, 0, 0);
            }
        }
    }

    __syncthreads();   // all waves done with As/Bs before Ost overlay
#pragma unroll
    for (int nt = 0; nt < 6; nt++) {
        int n = (ngrp + nt) * 16 + l16;
        float scale = (n < 64) ? LOG2E : 1.0f;   // q pre-scaled for exp2 softmax
#pragma unroll
        for (int reg = 0; reg < 4; reg++)
            Ostp[(16 * mstrip + quad * 4 + reg) * 200 + n] =
                (_Float16)((acc[nt][reg] + bvals[nt]) * scale);
    }
    __syncthreads();
    {
        const int mrow = tid >> 3, c0 = (tid & 7) * 8;
        _Float16* dsts[3] = {qh, kh, vh};
#pragma unroll
        for (int g = 0; g < 3; g++)
            *(h8*)(dsts[g] + (size_t)(row0 + mrow) * 64 + c0) =
                *(const h8*)(Ostp + mrow * 200 + g * 64 + c0);
    }
}

// ---------------- kernel 2: flash attention chunks; 128-row q-tile (2 strips/wave),
// K+V dbuf in LDS, transposed-S, XCD-clustered.
// R5: launch_bounds(256,3) — LDS 36.9KB allows 3 blocks/CU (110.6 <= 160KB); VGPR cap
// ~168 should hold the ~150-reg working set without spill. Occupancy 2->3 blocks/CU
// to overlap the per-k-tile barrier+vmcnt-drain serialization across more blocks.
__global__ __launch_bounds__(256, 3) void attn_kernel(
    const _Float16* __restrict__ qh, const _Float16* __restrict__ kh,
    const _Float16* __restrict__ vh, float* __restrict__ out,
    _Float16* __restrict__ Opart, float2* __restrict__ ml,
    int lgC, int NC1, int direct, int q8, int total)
{
    __shared__ _Float16 Ks[2][64][72];   // [buf][s][d]; reused as 128x72 O-staging
    __shared__ _Float16 Vt[2][64][72];   // [buf][p][s]
    const int tid = threadIdx.x;
    const int w = tid >> 6, lane = tid & 63, quad = lane >> 4, l16 = lane & 15;
    const int C = 1 << lgC;

    const int bid = blockIdx.x;
    const int cid = (bid & 7) * q8 + (bid >> 3);   // XCD clustering
    if (cid >= total) return;

    const int b = cid / NC1;
    int rem = cid - b * NC1;
    int qt2 = 0, k0 = 0, cnt = 1;
    for (int i = 0; i < 32; i++) {
        int nc = (2 * i + 2 + C - 1) >> lgC;
        if (rem < nc) { qt2 = i; k0 = rem << lgC; cnt = min(C, 2 * i + 2 - k0); break; }
        rem -= nc;
    }
    const size_t base = (size_t)b * T_ * 64;
    const int qbase = qt2 * 128 + w * 32;   // wave's first q-row

    // Q fragments for 2 strips (A/B layout: [l16][quad*8+j])
    h8 qf[2][2];
#pragma unroll
    for (int u = 0; u < 2; u++) {
        const _Float16* qp = qh + base + (size_t)(qbase + u * 16 + l16) * 64 + quad * 8;
        qf[u][0] = *(const h8*)qp;
        qf[u][1] = *(const h8*)(qp + 32);
    }

    f32x4 o[8];   // O^T tiles, C-layout: row=p(quad*4+reg), col=m(l16)
#pragma unroll
    for (int i = 0; i < 8; i++) o[i] = (f32x4){0.f, 0.f, 0.f, 0.f};
    float m[2] = {MINIT, MINIT}, l[2] = {0.f, 0.f};

    // staging maps
    const int krow = tid >> 3, kc0 = (tid & 7) * 8;          // K: 2 x h8 per thread
    const int vp0 = (tid & 15) * 4, vc0 = (tid >> 4) * 4;    // V: 4 x h4, reg transpose
    h8 kreg[2];
    h4 vreg[4];
    {
        const _Float16* kp = kh + base + (size_t)(k0 * 64) * 64;
        kreg[0] = *(const h8*)(kp + (size_t)krow * 64 + kc0);
        kreg[1] = *(const h8*)(kp + (size_t)(krow + 32) * 64 + kc0);
        const _Float16* vp = vh + base + (size_t)(k0 * 64 + vc0) * 64 + vp0;
#pragma unroll
        for (int i = 0; i < 4; i++) vreg[i] = *(const h4*)(vp + (size_t)i * 64);
    }

    const int kend = k0 + cnt;
    for (int kt = k0; kt < kend; kt++) {
        const int buf = kt & 1;
        *(h8*)&Ks[buf][krow][kc0] = kreg[0];
        *(h8*)&Ks[buf][krow + 32][kc0] = kreg[1];
#pragma unroll
        for (int j = 0; j < 4; j++) {
            h4 t;
            t[0] = vreg[0][j]; t[1] = vreg[1][j]; t[2] = vreg[2][j]; t[3] = vreg[3][j];
            *(h4*)&Vt[buf][vp0 + j][vc0] = t;
        }
        if (kt + 1 < kend) {   // prefetch next K/V tiles into regs
            const _Float16* kp = kh + base + (size_t)((kt + 1) * 64) * 64;
            kreg[0] = *(const h8*)(kp + (size_t)krow * 64 + kc0);
            kreg[1] = *(const h8*)(kp + (size_t)(krow + 32) * 64 + kc0);
            const _Float16* vp = vh + base + (size_t)((kt + 1) * 64 + vc0) * 64 + vp0;
#pragma unroll
            for (int i = 0; i < 4; i++) vreg[i] = *(const h4*)(vp + (size_t)i * 64);
        }
        __syncthreads();

        const bool skip = (kt * 64) > (qbase + 31);   // wave fully above diagonal
        if (!skip) {
            // S^T = K Q^T : D[s=quad*4+reg][m=l16], per strip u; kf shared across strips
            f32x4 s[2][4];
#pragma unroll
            for (int nt = 0; nt < 4; nt++) {
                h8 kf0 = *(const h8*)&Ks[buf][nt * 16 + l16][quad * 8];
                h8 kf1 = *(const h8*)&Ks[buf][nt * 16 + l16][32 + quad * 8];
#pragma unroll
                for (int u = 0; u < 2; u++) {
                    f32x4 c = (f32x4){0.f, 0.f, 0.f, 0.f};
                    c = __builtin_amdgcn_mfma_f32_16x16x32_f16(kf0, qf[u][0], c, 0, 0, 0);
                    c = __builtin_amdgcn_mfma_f32_16x16x32_f16(kf1, qf[u][1], c, 0, 0, 0);
                    s[u][nt] = c;
                }
            }

            h4 pf[2][4];
#pragma unroll
            for (int u = 0; u < 2; u++) {
                const int qrow = qbase + u * 16 + l16;
                if (kt * 64 + 63 > qbase + u * 16) {   // causal mask needed
#pragma unroll
                    for (int nt = 0; nt < 4; nt++)
#pragma unroll
                        for (int reg = 0; reg < 4; reg++) {
                            int sg = kt * 64 + nt * 16 + quad * 4 + reg;
                            if (sg > qrow) s[u][nt][reg] = MASKV;
                        }
                }
                float mx = s[u][0][0];
#pragma unroll
                for (int nt = 0; nt < 4; nt++)
#pragma unroll
                    for (int reg = 0; reg < 4; reg++) mx = fmaxf(mx, s[u][nt][reg]);
                mx = fmaxf(mx, __shfl_xor(mx, 16));
                mx = fmaxf(mx, __shfl_xor(mx, 32));
                float mnew = fmaxf(m[u], mx);
                float alpha = EXP2(m[u] - mnew);
                m[u] = mnew;
                float rs = 0.f;
#pragma unroll
                for (int nt = 0; nt < 4; nt++) {
                    h4 ph;
#pragma unroll
                    for (int reg = 0; reg < 4; reg++) {
                        float p = EXP2(s[u][nt][reg] - mnew);
                        rs += p;
                        ph[reg] = (_Float16)p;
                    }
                    pf[u][nt] = ph;
                }
                rs += __shfl_xor(rs, 16);
                rs += __shfl_xor(rs, 32);
                l[u] = l[u] * alpha + rs;
#pragma unroll
                for (int pt = 0; pt < 4; pt++)
#pragma unroll
                    for (int reg = 0; reg < 4; reg++) o[u * 4 + pt][reg] *= alpha;
            }

            // O^T += V^T P^T ; vf shared across strips
#pragma unroll
            for (int pt = 0; pt < 4; pt++)
#pragma unroll
                for (int nt = 0; nt < 4; nt++) {
                    h4 vf = *(const h4*)&Vt[buf][pt * 16 + l16][nt * 16 + quad * 4];
                    o[pt]     = __builtin_amdgcn_mfma_f32_16x16x16f16(vf, pf[0][nt], o[pt], 0, 0, 0);
                    o[4 + pt] = __builtin_amdgcn_mfma_f32_16x16x16f16(vf, pf[1][nt], o[4 + pt], 0, 0, 0);
                }
        }
    }

    if (direct) {
#pragma unroll
        for (int u = 0; u < 2; u++) {
            float linv = 1.0f / l[u];
            int trow = qt2 * 128 + w * 32 + u * 16 + l16;
#pragma unroll
            for (int pt = 0; pt < 4; pt++)
#pragma unroll
                for (int reg = 0; reg < 4; reg++)
                    out[base + (size_t)trow * 64 + pt * 16 + quad * 4 + reg] =
                        o[u * 4 + pt][reg] * linv;
        }
    } else {
        // stage O^T -> LDS -> coalesced h8 stores
        __syncthreads();                       // all waves done reading Ks/Vt
        _Float16* St = &Ks[0][0][0];           // 128 x 72 halfs (exactly 9216)
#pragma unroll
        for (int u = 0; u < 2; u++) {
            int r = w * 32 + u * 16 + l16;
#pragma unroll
            for (int pt = 0; pt < 4; pt++) {
                h4 ph;
#pragma unroll
                for (int reg = 0; reg < 4; reg++) ph[reg] = (_Float16)o[u * 4 + pt][reg];
                *(h4*)&St[r * 72 + pt * 16 + quad * 4] = ph;
            }
            if (quad == 0) ml[(size_t)cid * 128 + r] = make_float2(m[u], l[u]);
        }
        __syncthreads();
        _Float16* op = Opart + (size_t)cid * 8192;   // [128][64] f16
        const int r = tid >> 1, c0 = (tid & 1) * 32;
#pragma unroll
        for (int j = 0; j < 4; j++)
            *(h8*)(op + r * 64 + c0 + 8 * j) = *(const h8*)&St[r * 72 + c0 + 8 * j];
    }
}

// ---------------- kernel 3: merge split-K partials; grid 1024 (16-row groups)
__global__ __launch_bounds__(256) void combine_kernel(
    const _Float16* __restrict__ Opart, const float2* __restrict__ ml,
    float* __restrict__ out, int lgC, int NC1)
{
    const int C = 1 << lgC;
    const int task = blockIdx.x;                  // b(2b) | tile(5b) | rg(3b)
    const int b = task >> 8, tile = (task >> 3) & 31, rg = task & 7;
    int pref = 0;
    for (int i = 0; i < tile; i++) pref += (2 * i + 2 + C - 1) >> lgC;
    const int cbase = b * NC1 + pref;
    const int nch = (2 * tile + 2 + C - 1) >> lgC;

    const int r = rg * 16 + (threadIdx.x >> 4);   // local row in [0,128)
    const int c0 = (threadIdx.x & 15) * 4;

    float M = MINIT;
    for (int i = 0; i < nch; i++) M = fmaxf(M, ml[(size_t)(cbase + i) * 128 + r].x);
    float L = 0.f, acc[4] = {0.f, 0.f, 0.f, 0.f};
    for (int i = 0; i < nch; i++) {
        float2 v = ml[(size_t)(cbase + i) * 128 + r];
        float sc = EXP2(v.x - M);
        L += sc * v.y;
        h4 x4 = *(const h4*)(Opart + (size_t)(cbase + i) * 8192 + (size_t)r * 64 + c0);
#pragma unroll
        for (int t = 0; t < 4; t++) acc[t] += sc * (float)x4[t];
    }
    float inv = 1.0f / L;
    float4 res = { acc[0]*inv, acc[1]*inv, acc[2]*inv, acc[3]*inv };
    *(float4*)(out + ((size_t)b * T_ + tile * 128 + r) * 64 + c0) = res;
}

extern "C" void kernel_launch(void* const* d_in, const int* in_sizes, int n_in,
                              void* d_out, int out_size, void* d_ws, size_t ws_size,
                              hipStream_t stream) {
    const float* x    = (const float*)d_in[0];
    const float* W    = (const float*)d_in[1];
    const float* bias = (const float*)d_in[2];
    float* out = (float*)d_out;
    char* ws = (char*)d_ws;
    _Float16* qh = (_Float16*)(ws);
    _Float16* kh = (_Float16*)(ws + (size_t)2 * 1024 * 1024);
    _Float16* vh = (_Float16*)(ws + (size_t)4 * 1024 * 1024);
    _Float16* Wt = (_Float16*)(ws + (size_t)6 * 1024 * 1024);
    const size_t pbase = (size_t)8 * 1024 * 1024;

    // smallest C whose f16 partials fit in ws (128-row tiles)
    int lgC = -1, nc1 = 32;
    for (int lg = 2; lg <= 6; lg++) {
        int C = 1 << lg, n1 = 0;
        for (int i = 0; i < 32; i++) n1 += (2 * i + 2 + C - 1) >> lg;
        size_t need = pbase + (size_t)4 * n1 * (8192 * 2 + 128 * 8);
        if (need <= ws_size) { lgC = lg; nc1 = n1; break; }
    }
    int direct = (lgC < 0) ? 1 : 0;
    if (direct) { lgC = 6; nc1 = 32; }
    _Float16* Opart = (_Float16*)(ws + pbase);
    float2*   mlp   = (float2*)(ws + pbase + (size_t)4 * nc1 * 8192 * 2);

    const int total = 4 * nc1;
    const int q8 = (total + 7) / 8;

    wt_kernel<<<64, 256, 0, stream>>>(W, Wt);
    proj_kernel<<<512, 256, 0, stream>>>(x, Wt, bias, qh, kh, vh);
    attn_kernel<<<8 * q8, 256, 0, stream>>>(qh, kh, vh, out, Opart, mlp,
                                            lgC, nc1, direct, q8, total);
    if (!direct)
        combine_kernel<<<1024, 256, 0, stream>>>(Opart, mlp, out, lgC, nc1);
}

// Round 6
// 145.168 us; speedup vs baseline: 1.1111x; 1.0035x over previous
//
#include <hip/hip_runtime.h>
#include <hip/hip_fp16.h>

#define B_ 4
#define T_ 4096
#define D_ 1024

typedef _Float16 h8 __attribute__((ext_vector_type(8)));
typedef _Float16 h4 __attribute__((ext_vector_type(4)));
typedef float f32x4 __attribute__((ext_vector_type(4)));

#define LOG2E 1.44269504088896340736f
#define MASKV -3.0e38f
#define MINIT -1.0e30f
#define EXP2(x) __builtin_amdgcn_exp2f(x)

// ---------------- kernel 0: W (1024x192 f32) -> Wt (192x1024 f16), LDS transpose
__global__ __launch_bounds__(256) void wt_kernel(const float* __restrict__ W,
                                                 _Float16* __restrict__ Wt) {
    __shared__ _Float16 Tr[192][20];
    const int tid = threadIdx.x, k0 = blockIdx.x * 16;   // grid 64
#pragma unroll
    for (int i = 0; i < 3; i++) {
        int fi = tid + 256 * i;                 // 768 float4 = 16 rows x 48
        int r = fi / 48, c4 = fi % 48;
        float4 v = *(const float4*)(W + (size_t)(k0 + r) * 192 + c4 * 4);
        Tr[c4 * 4 + 0][r] = (_Float16)v.x;
        Tr[c4 * 4 + 1][r] = (_Float16)v.y;
        Tr[c4 * 4 + 2][r] = (_Float16)v.z;
        Tr[c4 * 4 + 3][r] = (_Float16)v.w;
    }
    __syncthreads();
#pragma unroll
    for (int i = 0; i < 3; i++) {
        int oi = tid + 256 * i;                 // 768 h4 = 192 rows x 4
        int n = oi >> 2, kq = oi & 3;
        *(h4*)(Wt + (size_t)n * D_ + k0 + kq * 4) = *(const h4*)&Tr[n][kq * 4];
    }
}

// ---------------- kernel 1: qkv projection, BM=32 BN=192, BK=128 (8 chunks),
// single-buffer LDS (A[32][136] + B[192][136] = 60.9 KB -> 2 blocks/CU), chunk-deep
// register prefetch issued after the stage barrier (R4-verified: proj ~42.5 -> ~17us).
__global__ __launch_bounds__(256, 2) void proj_kernel(
    const float* __restrict__ x, const _Float16* __restrict__ Wt,
    const float* __restrict__ bias,
    _Float16* __restrict__ qh, _Float16* __restrict__ kh, _Float16* __restrict__ vh)
{
    __shared__ __align__(16) char psm[60928];
    _Float16* Asp = (_Float16*)psm;             // [32][136]
    _Float16* Bsp = (_Float16*)(psm + 8704);    // [192][136]
    _Float16* Ostp = (_Float16*)psm;            // [32][200] epilogue overlay
    const int tid = threadIdx.x;
    const int w = tid >> 6, lane = tid & 63, quad = lane >> 4, l16 = lane & 15;
    const int row0 = blockIdx.x * 32;
    const int mstrip = w & 1;
    const int ngrp = (w >> 1) * 6;

    float bvals[6];
#pragma unroll
    for (int nt = 0; nt < 6; nt++) bvals[nt] = bias[(ngrp + nt) * 16 + l16];

    f32x4 acc[6];
#pragma unroll
    for (int i = 0; i < 6; i++) acc[i] = (f32x4){0.f, 0.f, 0.f, 0.f};

    // staging maps: A: 4 float4/thread (32 rows x 128 cols f32)
    //               B: 12 h8/thread  (192 rows x 128 cols f16)
    const int arow = tid >> 3, ac = (tid & 7) * 4;
    const float* xrow = x + (size_t)(row0 + arow) * D_;

    float4 xa[4];
    h8 wreg[12];
    // prologue: chunk 0 loads
#pragma unroll
    for (int p = 0; p < 4; p++) xa[p] = *(const float4*)(xrow + p * 32 + ac);
#pragma unroll
    for (int p = 0; p < 12; p++) {
        int f = tid + 256 * p; int n = f >> 4, c = (f & 15) * 8;
        wreg[p] = *(const h8*)(Wt + (size_t)n * D_ + c);
    }

    for (int it = 0; it < 8; it++) {
        if (it) __syncthreads();           // all waves done reading previous chunk
        // stage regs -> LDS
#pragma unroll
        for (int p = 0; p < 4; p++) {
            h4 av;
            av[0] = (_Float16)xa[p].x; av[1] = (_Float16)xa[p].y;
            av[2] = (_Float16)xa[p].z; av[3] = (_Float16)xa[p].w;
            *(h4*)(Asp + arow * 136 + p * 32 + ac) = av;
        }
#pragma unroll
        for (int p = 0; p < 12; p++) {
            int f = tid + 256 * p; int n = f >> 4, c = (f & 15) * 8;
            *(h8*)(Bsp + n * 136 + c) = wreg[p];
        }
        __syncthreads();
        if (it + 1 < 8) {                  // prefetch next chunk; lands during compute
            const int k0 = (it + 1) * 128;
#pragma unroll
            for (int p = 0; p < 4; p++) xa[p] = *(const float4*)(xrow + k0 + p * 32 + ac);
#pragma unroll
            for (int p = 0; p < 12; p++) {
                int f = tid + 256 * p; int n = f >> 4, c = (f & 15) * 8;
                wreg[p] = *(const h8*)(Wt + (size_t)n * D_ + k0 + c);
            }
        }
        // compute: 4 K-slices of 32, 6 N-tiles each
#pragma unroll
        for (int kk = 0; kk < 4; kk++) {
            h8 a0 = *(const h8*)(Asp + (16 * mstrip + l16) * 136 + kk * 32 + quad * 8);
#pragma unroll
            for (int nt = 0; nt < 6; nt++) {
                h8 b0 = *(const h8*)(Bsp + ((ngrp + nt) * 16 + l16) * 136 + kk * 32 + quad * 8);
                acc[nt] = __builtin_amdgcn_mfma_f32_16x16x32_f16(a0, b0, acc[nt], 0, 0, 0);
            }
        }
    }

    __syncthreads();   // all waves done with As/Bs before Ost overlay
#pragma unroll
    for (int nt = 0; nt < 6; nt++) {
        int n = (ngrp + nt) * 16 + l16;
        float scale = (n < 64) ? LOG2E : 1.0f;   // q pre-scaled for exp2 softmax
#pragma unroll
        for (int reg = 0; reg < 4; reg++)
            Ostp[(16 * mstrip + quad * 4 + reg) * 200 + n] =
                (_Float16)((acc[nt][reg] + bvals[nt]) * scale);
    }
    __syncthreads();
    {
        const int mrow = tid >> 3, c0 = (tid & 7) * 8;
        _Float16* dsts[3] = {qh, kh, vh};
#pragma unroll
        for (int g = 0; g < 3; g++)
            *(h8*)(dsts[g] + (size_t)(row0 + mrow) * 64 + c0) =
                *(const h8*)(Ostp + mrow * 200 + g * 64 + c0);
    }
}

// ---------------- kernel 2: flash attention chunks; 128-row q-tile (2 strips/wave),
// K+V dbuf in LDS, transposed-S, XCD-clustered. launch_bounds(256,3) (R5: neutral,
// kept). R6: T13 defer-max (wave-vote skip of m-update + o-rescale when tile max
// doesn't grow by >8 in log2 domain) + T5 setprio around MFMA clusters.
__global__ __launch_bounds__(256, 3) void attn_kernel(
    const _Float16* __restrict__ qh, const _Float16* __restrict__ kh,
    const _Float16* __restrict__ vh, float* __restrict__ out,
    _Float16* __restrict__ Opart, float2* __restrict__ ml,
    int lgC, int NC1, int direct, int q8, int total)
{
    __shared__ _Float16 Ks[2][64][72];   // [buf][s][d]; reused as 128x72 O-staging
    __shared__ _Float16 Vt[2][64][72];   // [buf][p][s]
    const int tid = threadIdx.x;
    const int w = tid >> 6, lane = tid & 63, quad = lane >> 4, l16 = lane & 15;
    const int C = 1 << lgC;

    const int bid = blockIdx.x;
    const int cid = (bid & 7) * q8 + (bid >> 3);   // XCD clustering
    if (cid >= total) return;

    const int b = cid / NC1;
    int rem = cid - b * NC1;
    int qt2 = 0, k0 = 0, cnt = 1;
    for (int i = 0; i < 32; i++) {
        int nc = (2 * i + 2 + C - 1) >> lgC;
        if (rem < nc) { qt2 = i; k0 = rem << lgC; cnt = min(C, 2 * i + 2 - k0); break; }
        rem -= nc;
    }
    const size_t base = (size_t)b * T_ * 64;
    const int qbase = qt2 * 128 + w * 32;   // wave's first q-row

    // Q fragments for 2 strips (A/B layout: [l16][quad*8+j])
    h8 qf[2][2];
#pragma unroll
    for (int u = 0; u < 2; u++) {
        const _Float16* qp = qh + base + (size_t)(qbase + u * 16 + l16) * 64 + quad * 8;
        qf[u][0] = *(const h8*)qp;
        qf[u][1] = *(const h8*)(qp + 32);
    }

    f32x4 o[8];   // O^T tiles, C-layout: row=p(quad*4+reg), col=m(l16)
#pragma unroll
    for (int i = 0; i < 8; i++) o[i] = (f32x4){0.f, 0.f, 0.f, 0.f};
    float m[2] = {MINIT, MINIT}, l[2] = {0.f, 0.f};

    // staging maps
    const int krow = tid >> 3, kc0 = (tid & 7) * 8;          // K: 2 x h8 per thread
    const int vp0 = (tid & 15) * 4, vc0 = (tid >> 4) * 4;    // V: 4 x h4, reg transpose
    h8 kreg[2];
    h4 vreg[4];
    {
        const _Float16* kp = kh + base + (size_t)(k0 * 64) * 64;
        kreg[0] = *(const h8*)(kp + (size_t)krow * 64 + kc0);
        kreg[1] = *(const h8*)(kp + (size_t)(krow + 32) * 64 + kc0);
        const _Float16* vp = vh + base + (size_t)(k0 * 64 + vc0) * 64 + vp0;
#pragma unroll
        for (int i = 0; i < 4; i++) vreg[i] = *(const h4*)(vp + (size_t)i * 64);
    }

    const int kend = k0 + cnt;
    for (int kt = k0; kt < kend; kt++) {
        const int buf = kt & 1;
        *(h8*)&Ks[buf][krow][kc0] = kreg[0];
        *(h8*)&Ks[buf][krow + 32][kc0] = kreg[1];
#pragma unroll
        for (int j = 0; j < 4; j++) {
            h4 t;
            t[0] = vreg[0][j]; t[1] = vreg[1][j]; t[2] = vreg[2][j]; t[3] = vreg[3][j];
            *(h4*)&Vt[buf][vp0 + j][vc0] = t;
        }
        if (kt + 1 < kend) {   // prefetch next K/V tiles into regs
            const _Float16* kp = kh + base + (size_t)((kt + 1) * 64) * 64;
            kreg[0] = *(const h8*)(kp + (size_t)krow * 64 + kc0);
            kreg[1] = *(const h8*)(kp + (size_t)(krow + 32) * 64 + kc0);
            const _Float16* vp = vh + base + (size_t)((kt + 1) * 64 + vc0) * 64 + vp0;
#pragma unroll
            for (int i = 0; i < 4; i++) vreg[i] = *(const h4*)(vp + (size_t)i * 64);
        }
        __syncthreads();

        const bool skip = (kt * 64) > (qbase + 31);   // wave fully above diagonal
        if (!skip) {
            // S^T = K Q^T : D[s=quad*4+reg][m=l16], per strip u; kf shared across strips
            f32x4 s[2][4];
            __builtin_amdgcn_s_setprio(1);
#pragma unroll
            for (int nt = 0; nt < 4; nt++) {
                h8 kf0 = *(const h8*)&Ks[buf][nt * 16 + l16][quad * 8];
                h8 kf1 = *(const h8*)&Ks[buf][nt * 16 + l16][32 + quad * 8];
#pragma unroll
                for (int u = 0; u < 2; u++) {
                    f32x4 c = (f32x4){0.f, 0.f, 0.f, 0.f};
                    c = __builtin_amdgcn_mfma_f32_16x16x32_f16(kf0, qf[u][0], c, 0, 0, 0);
                    c = __builtin_amdgcn_mfma_f32_16x16x32_f16(kf1, qf[u][1], c, 0, 0, 0);
                    s[u][nt] = c;
                }
            }
            __builtin_amdgcn_s_setprio(0);

            h4 pf[2][4];
#pragma unroll
            for (int u = 0; u < 2; u++) {
                const int qrow = qbase + u * 16 + l16;
                if (kt * 64 + 63 > qbase + u * 16) {   // causal mask needed
#pragma unroll
                    for (int nt = 0; nt < 4; nt++)
#pragma unroll
                        for (int reg = 0; reg < 4; reg++) {
                            int sg = kt * 64 + nt * 16 + quad * 4 + reg;
                            if (sg > qrow) s[u][nt][reg] = MASKV;
                        }
                }
                float mx = s[u][0][0];
#pragma unroll
                for (int nt = 0; nt < 4; nt++)
#pragma unroll
                    for (int reg = 0; reg < 4; reg++) mx = fmaxf(mx, s[u][nt][reg]);
                mx = fmaxf(mx, __shfl_xor(mx, 16));
                mx = fmaxf(mx, __shfl_xor(mx, 32));
                // T13 defer-max: wave-uniform vote; skip m-update + rescale when the
                // tile max doesn't exceed running max by >8 (log2 domain, P <= 2^8).
                if (!__all(mx <= m[u] + 8.0f)) {
                    float mnew = fmaxf(m[u], mx);
                    float alpha = EXP2(m[u] - mnew);
                    m[u] = mnew;
                    l[u] *= alpha;
#pragma unroll
                    for (int pt = 0; pt < 4; pt++)
#pragma unroll
                        for (int reg = 0; reg < 4; reg++) o[u * 4 + pt][reg] *= alpha;
                }
                float rs = 0.f;
#pragma unroll
                for (int nt = 0; nt < 4; nt++) {
                    h4 ph;
#pragma unroll
                    for (int reg = 0; reg < 4; reg++) {
                        float p = EXP2(s[u][nt][reg] - m[u]);
                        rs += p;
                        ph[reg] = (_Float16)p;
                    }
                    pf[u][nt] = ph;
                }
                rs += __shfl_xor(rs, 16);
                rs += __shfl_xor(rs, 32);
                l[u] += rs;
            }

            // O^T += V^T P^T ; vf shared across strips
            __builtin_amdgcn_s_setprio(1);
#pragma unroll
            for (int pt = 0; pt < 4; pt++)
#pragma unroll
                for (int nt = 0; nt < 4; nt++) {
                    h4 vf = *(const h4*)&Vt[buf][pt * 16 + l16][nt * 16 + quad * 4];
                    o[pt]     = __builtin_amdgcn_mfma_f32_16x16x16f16(vf, pf[0][nt], o[pt], 0, 0, 0);
                    o[4 + pt] = __builtin_amdgcn_mfma_f32_16x16x16f16(vf, pf[1][nt], o[4 + pt], 0, 0, 0);
                }
            __builtin_amdgcn_s_setprio(0);
        }
    }

    if (direct) {
#pragma unroll
        for (int u = 0; u < 2; u++) {
            float linv = 1.0f / l[u];
            int trow = qt2 * 128 + w * 32 + u * 16 + l16;
#pragma unroll
            for (int pt = 0; pt < 4; pt++)
#pragma unroll
                for (int reg = 0; reg < 4; reg++)
                    out[base + (size_t)trow * 64 + pt * 16 + quad * 4 + reg] =
                        o[u * 4 + pt][reg] * linv;
        }
    } else {
        // stage O^T -> LDS -> coalesced h8 stores
        __syncthreads();                       // all waves done reading Ks/Vt
        _Float16* St = &Ks[0][0][0];           // 128 x 72 halfs (exactly 9216)
#pragma unroll
        for (int u = 0; u < 2; u++) {
            int r = w * 32 + u * 16 + l16;
#pragma unroll
            for (int pt = 0; pt < 4; pt++) {
                h4 ph;
#pragma unroll
                for (int reg = 0; reg < 4; reg++) ph[reg] = (_Float16)o[u * 4 + pt][reg];
                *(h4*)&St[r * 72 + pt * 16 + quad * 4] = ph;
            }
            if (quad == 0) ml[(size_t)cid * 128 + r] = make_float2(m[u], l[u]);
        }
        __syncthreads();
        _Float16* op = Opart + (size_t)cid * 8192;   // [128][64] f16
        const int r = tid >> 1, c0 = (tid & 1) * 32;
#pragma unroll
        for (int j = 0; j < 4; j++)
            *(h8*)(op + r * 64 + c0 + 8 * j) = *(const h8*)&St[r * 72 + c0 + 8 * j];
    }
}

// ---------------- kernel 3: merge split-K partials; grid 1024 (16-row groups)
__global__ __launch_bounds__(256) void combine_kernel(
    const _Float16* __restrict__ Opart, const float2* __restrict__ ml,
    float* __restrict__ out, int lgC, int NC1)
{
    const int C = 1 << lgC;
    const int task = blockIdx.x;                  // b(2b) | tile(5b) | rg(3b)
    const int b = task >> 8, tile = (task >> 3) & 31, rg = task & 7;
    int pref = 0;
    for (int i = 0; i < tile; i++) pref += (2 * i + 2 + C - 1) >> lgC;
    const int cbase = b * NC1 + pref;
    const int nch = (2 * tile + 2 + C - 1) >> lgC;

    const int r = rg * 16 + (threadIdx.x >> 4);   // local row in [0,128)
    const int c0 = (threadIdx.x & 15) * 4;

    float M = MINIT;
    for (int i = 0; i < nch; i++) M = fmaxf(M, ml[(size_t)(cbase + i) * 128 + r].x);
    float L = 0.f, acc[4] = {0.f, 0.f, 0.f, 0.f};
    for (int i = 0; i < nch; i++) {
        float2 v = ml[(size_t)(cbase + i) * 128 + r];
        float sc = EXP2(v.x - M);
        L += sc * v.y;
        h4 x4 = *(const h4*)(Opart + (size_t)(cbase + i) * 8192 + (size_t)r * 64 + c0);
#pragma unroll
        for (int t = 0; t < 4; t++) acc[t] += sc * (float)x4[t];
    }
    float inv = 1.0f / L;
    float4 res = { acc[0]*inv, acc[1]*inv, acc[2]*inv, acc[3]*inv };
    *(float4*)(out + ((size_t)b * T_ + tile * 128 + r) * 64 + c0) = res;
}

extern "C" void kernel_launch(void* const* d_in, const int* in_sizes, int n_in,
                              void* d_out, int out_size, void* d_ws, size_t ws_size,
                              hipStream_t stream) {
    const float* x    = (const float*)d_in[0];
    const float* W    = (const float*)d_in[1];
    const float* bias = (const float*)d_in[2];
    float* out = (float*)d_out;
    char* ws = (char*)d_ws;
    _Float16* qh = (_Float16*)(ws);
    _Float16* kh = (_Float16*)(ws + (size_t)2 * 1024 * 1024);
    _Float16* vh = (_Float16*)(ws + (size_t)4 * 1024 * 1024);
    _Float16* Wt = (_Float16*)(ws + (size_t)6 * 1024 * 1024);
    const size_t pbase = (size_t)8 * 1024 * 1024;

    // smallest C whose f16 partials fit in ws (128-row tiles)
    int lgC = -1, nc1 = 32;
    for (int lg = 2; lg <= 6; lg++) {
        int C = 1 << lg, n1 = 0;
        for (int i = 0; i < 32; i++) n1 += (2 * i + 2 + C - 1) >> lg;
        size_t need = pbase + (size_t)4 * n1 * (8192 * 2 + 128 * 8);
        if (need <= ws_size) { lgC = lg; nc1 = n1; break; }
    }
    int direct = (lgC < 0) ? 1 : 0;
    if (direct) { lgC = 6; nc1 = 32; }
    _Float16* Opart = (_Float16*)(ws + pbase);
    float2*   mlp   = (float2*)(ws + pbase + (size_t)4 * nc1 * 8192 * 2);

    const int total = 4 * nc1;
    const int q8 = (total + 7) / 8;

    wt_kernel<<<64, 256, 0, stream>>>(W, Wt);
    proj_kernel<<<512, 256, 0, stream>>>(x, Wt, bias, qh, kh, vh);
    attn_kernel<<<8 * q8, 256, 0, stream>>>(qh, kh, vh, out, Opart, mlp,
                                            lgC, nc1, direct, q8, total);
    if (!direct)
        combine_kernel<<<1024, 256, 0, stream>>>(Opart, mlp, out, lgC, nc1);
}

// Round 9
// 143.841 us; speedup vs baseline: 1.1213x; 1.0092x over previous
//
#include <hip/hip_runtime.h>
#include <hip/hip_fp16.h>

#define B_ 4
#define T_ 4096
#define D_ 1024

typedef _Float16 h8 __attribute__((ext_vector_type(8)));
typedef _Float16 h4 __attribute__((ext_vector_type(4)));
typedef float f32x4 __attribute__((ext_vector_type(4)));

#define LOG2E 1.44269504088896340736f
#define MASKV -3.0e38f
#define MINIT -1.0e30f
#define EXP2(x) __builtin_amdgcn_exp2f(x)

// ---------------- kernel 0: W (1024x192 f32) -> Wt (192x1024 f16), LDS transpose
__global__ __launch_bounds__(256) void wt_kernel(const float* __restrict__ W,
                                                 _Float16* __restrict__ Wt) {
    __shared__ _Float16 Tr[192][20];
    const int tid = threadIdx.x, k0 = blockIdx.x * 16;   // grid 64
#pragma unroll
    for (int i = 0; i < 3; i++) {
        int fi = tid + 256 * i;                 // 768 float4 = 16 rows x 48
        int r = fi / 48, c4 = fi % 48;
        float4 v = *(const float4*)(W + (size_t)(k0 + r) * 192 + c4 * 4);
        Tr[c4 * 4 + 0][r] = (_Float16)v.x;
        Tr[c4 * 4 + 1][r] = (_Float16)v.y;
        Tr[c4 * 4 + 2][r] = (_Float16)v.z;
        Tr[c4 * 4 + 3][r] = (_Float16)v.w;
    }
    __syncthreads();
#pragma unroll
    for (int i = 0; i < 3; i++) {
        int oi = tid + 256 * i;                 // 768 h4 = 192 rows x 4
        int n = oi >> 2, kq = oi & 3;
        *(h4*)(Wt + (size_t)n * D_ + k0 + kq * 4) = *(const h4*)&Tr[n][kq * 4];
    }
}

// ---------------- kernel 1: qkv projection, BM=32 BN=192, BK=128 (8 chunks),
// single-buffer LDS (A[32][136] + B[192][136] = 60.9 KB -> 2 blocks/CU), chunk-deep
// register prefetch after the stage barrier (R4: proj 42.5 -> ~30us).
// R7: wave-retile 1m x 6n -> 2m x 3n: per K-slice 2 A-reads + 3 B-reads for 6 MFMA
// (was 1+6) -> -29% ds_read_b128 in the compute phase (proj is LDS-pipe-bound).
__global__ __launch_bounds__(256, 2) void proj_kernel(
    const float* __restrict__ x, const _Float16* __restrict__ Wt,
    const float* __restrict__ bias,
    _Float16* __restrict__ qh, _Float16* __restrict__ kh, _Float16* __restrict__ vh)
{
    __shared__ __align__(16) char psm[60928];
    _Float16* Asp = (_Float16*)psm;             // [32][136]
    _Float16* Bsp = (_Float16*)(psm + 8704);    // [192][136]
    _Float16* Ostp = (_Float16*)psm;            // [32][200] epilogue overlay
    const int tid = threadIdx.x;
    const int w = tid >> 6, lane = tid & 63, quad = lane >> 4, l16 = lane & 15;
    const int row0 = blockIdx.x * 32;
    const int ng3 = w * 3;                      // wave's 3 N-tiles (48 cols)

    float bvals[3];
#pragma unroll
    for (int nt = 0; nt < 3; nt++) bvals[nt] = bias[(ng3 + nt) * 16 + l16];

    f32x4 acc[2][3];
#pragma unroll
    for (int u = 0; u < 2; u++)
#pragma unroll
        for (int i = 0; i < 3; i++) acc[u][i] = (f32x4){0.f, 0.f, 0.f, 0.f};

    // staging maps: A: 4 float4/thread (32 rows x 128 cols f32)
    //               B: 12 h8/thread  (192 rows x 128 cols f16)
    const int arow = tid >> 3, ac = (tid & 7) * 4;
    const float* xrow = x + (size_t)(row0 + arow) * D_;

    float4 xa[4];
    h8 wreg[12];
    // prologue: chunk 0 loads
#pragma unroll
    for (int p = 0; p < 4; p++) xa[p] = *(const float4*)(xrow + p * 32 + ac);
#pragma unroll
    for (int p = 0; p < 12; p++) {
        int f = tid + 256 * p; int n = f >> 4, c = (f & 15) * 8;
        wreg[p] = *(const h8*)(Wt + (size_t)n * D_ + c);
    }

    for (int it = 0; it < 8; it++) {
        if (it) __syncthreads();           // all waves done reading previous chunk
        // stage regs -> LDS
#pragma unroll
        for (int p = 0; p < 4; p++) {
            h4 av;
            av[0] = (_Float16)xa[p].x; av[1] = (_Float16)xa[p].y;
            av[2] = (_Float16)xa[p].z; av[3] = (_Float16)xa[p].w;
            *(h4*)(Asp + arow * 136 + p * 32 + ac) = av;
        }
#pragma unroll
        for (int p = 0; p < 12; p++) {
            int f = tid + 256 * p; int n = f >> 4, c = (f & 15) * 8;
            *(h8*)(Bsp + n * 136 + c) = wreg[p];
        }
        __syncthreads();
        if (it + 1 < 8) {                  // prefetch next chunk; lands during compute
            const int k0 = (it + 1) * 128;
#pragma unroll
            for (int p = 0; p < 4; p++) xa[p] = *(const float4*)(xrow + k0 + p * 32 + ac);
#pragma unroll
            for (int p = 0; p < 12; p++) {
                int f = tid + 256 * p; int n = f >> 4, c = (f & 15) * 8;
                wreg[p] = *(const h8*)(Wt + (size_t)n * D_ + k0 + c);
            }
        }
        // compute: 4 K-slices of 32; 2 M-strips x 3 N-tiles per wave
#pragma unroll
        for (int kk = 0; kk < 4; kk++) {
            h8 a0 = *(const h8*)(Asp + l16 * 136 + kk * 32 + quad * 8);
            h8 a1 = *(const h8*)(Asp + (16 + l16) * 136 + kk * 32 + quad * 8);
#pragma unroll
            for (int nt = 0; nt < 3; nt++) {
                h8 b0 = *(const h8*)(Bsp + ((ng3 + nt) * 16 + l16) * 136 + kk * 32 + quad * 8);
                acc[0][nt] = __builtin_amdgcn_mfma_f32_16x16x32_f16(a0, b0, acc[0][nt], 0, 0, 0);
                acc[1][nt] = __builtin_amdgcn_mfma_f32_16x16x32_f16(a1, b0, acc[1][nt], 0, 0, 0);
            }
        }
    }

    __syncthreads();   // all waves done with As/Bs before Ost overlay
#pragma unroll
    for (int u = 0; u < 2; u++)
#pragma unroll
        for (int nt = 0; nt < 3; nt++) {
            int n = (ng3 + nt) * 16 + l16;
            float scale = (n < 64) ? LOG2E : 1.0f;   // q pre-scaled for exp2 softmax
#pragma unroll
            for (int reg = 0; reg < 4; reg++)
                Ostp[(16 * u + quad * 4 + reg) * 200 + n] =
                    (_Float16)((acc[u][nt][reg] + bvals[nt]) * scale);
        }
    __syncthreads();
    {
        const int mrow = tid >> 3, c0 = (tid & 7) * 8;
        _Float16* dsts[3] = {qh, kh, vh};
#pragma unroll
        for (int g = 0; g < 3; g++)
            *(h8*)(dsts[g] + (size_t)(row0 + mrow) * 64 + c0) =
                *(const h8*)(Ostp + mrow * 200 + g * 64 + c0);
    }
}

// ---------------- kernel 2: flash attention chunks; 128-row q-tile (2 strips/wave),
// K+V dbuf in LDS, transposed-S, XCD-clustered. launch_bounds(256,3).
// R6: T13 defer-max + T5 setprio (neutral, kept). R7: C=8 (half the chunks ->
// half the partials traffic and per-chunk fixed overhead).
__global__ __launch_bounds__(256, 3) void attn_kernel(
    const _Float16* __restrict__ qh, const _Float16* __restrict__ kh,
    const _Float16* __restrict__ vh, float* __restrict__ out,
    _Float16* __restrict__ Opart, float2* __restrict__ ml,
    int lgC, int NC1, int direct, int q8, int total)
{
    __shared__ _Float16 Ks[2][64][72];   // [buf][s][d]; reused as 128x72 O-staging
    __shared__ _Float16 Vt[2][64][72];   // [buf][p][s]
    const int tid = threadIdx.x;
    const int w = tid >> 6, lane = tid & 63, quad = lane >> 4, l16 = lane & 15;
    const int C = 1 << lgC;

    const int bid = blockIdx.x;
    const int cid = (bid & 7) * q8 + (bid >> 3);   // XCD clustering
    if (cid >= total) return;

    const int b = cid / NC1;
    int rem = cid - b * NC1;
    int qt2 = 0, k0 = 0, cnt = 1;
    for (int i = 0; i < 32; i++) {
        int nc = (2 * i + 2 + C - 1) >> lgC;
        if (rem < nc) { qt2 = i; k0 = rem << lgC; cnt = min(C, 2 * i + 2 - k0); break; }
        rem -= nc;
    }
    const size_t base = (size_t)b * T_ * 64;
    const int qbase = qt2 * 128 + w * 32;   // wave's first q-row

    // Q fragments for 2 strips (A/B layout: [l16][quad*8+j])
    h8 qf[2][2];
#pragma unroll
    for (int u = 0; u < 2; u++) {
        const _Float16* qp = qh + base + (size_t)(qbase + u * 16 + l16) * 64 + quad * 8;
        qf[u][0] = *(const h8*)qp;
        qf[u][1] = *(const h8*)(qp + 32);
    }

    f32x4 o[8];   // O^T tiles, C-layout: row=p(quad*4+reg), col=m(l16)
#pragma unroll
    for (int i = 0; i < 8; i++) o[i] = (f32x4){0.f, 0.f, 0.f, 0.f};
    float m[2] = {MINIT, MINIT}, l[2] = {0.f, 0.f};

    // staging maps
    const int krow = tid >> 3, kc0 = (tid & 7) * 8;          // K: 2 x h8 per thread
    const int vp0 = (tid & 15) * 4, vc0 = (tid >> 4) * 4;    // V: 4 x h4, reg transpose
    h8 kreg[2];
    h4 vreg[4];
    {
        const _Float16* kp = kh + base + (size_t)(k0 * 64) * 64;
        kreg[0] = *(const h8*)(kp + (size_t)krow * 64 + kc0);
        kreg[1] = *(const h8*)(kp + (size_t)(krow + 32) * 64 + kc0);
        const _Float16* vp = vh + base + (size_t)(k0 * 64 + vc0) * 64 + vp0;
#pragma unroll
        for (int i = 0; i < 4; i++) vreg[i] = *(const h4*)(vp + (size_t)i * 64);
    }

    const int kend = k0 + cnt;
    for (int kt = k0; kt < kend; kt++) {
        const int buf = kt & 1;
        *(h8*)&Ks[buf][krow][kc0] = kreg[0];
        *(h8*)&Ks[buf][krow + 32][kc0] = kreg[1];
#pragma unroll
        for (int j = 0; j < 4; j++) {
            h4 t;
            t[0] = vreg[0][j]; t[1] = vreg[1][j]; t[2] = vreg[2][j]; t[3] = vreg[3][j];
            *(h4*)&Vt[buf][vp0 + j][vc0] = t;
        }
        if (kt + 1 < kend) {   // prefetch next K/V tiles into regs
            const _Float16* kp = kh + base + (size_t)((kt + 1) * 64) * 64;
            kreg[0] = *(const h8*)(kp + (size_t)krow * 64 + kc0);
            kreg[1] = *(const h8*)(kp + (size_t)(krow + 32) * 64 + kc0);
            const _Float16* vp = vh + base + (size_t)((kt + 1) * 64 + vc0) * 64 + vp0;
#pragma unroll
            for (int i = 0; i < 4; i++) vreg[i] = *(const h4*)(vp + (size_t)i * 64);
        }
        __syncthreads();

        const bool skip = (kt * 64) > (qbase + 31);   // wave fully above diagonal
        if (!skip) {
            // S^T = K Q^T : D[s=quad*4+reg][m=l16], per strip u; kf shared across strips
            f32x4 s[2][4];
            __builtin_amdgcn_s_setprio(1);
#pragma unroll
            for (int nt = 0; nt < 4; nt++) {
                h8 kf0 = *(const h8*)&Ks[buf][nt * 16 + l16][quad * 8];
                h8 kf1 = *(const h8*)&Ks[buf][nt * 16 + l16][32 + quad * 8];
#pragma unroll
                for (int u = 0; u < 2; u++) {
                    f32x4 c = (f32x4){0.f, 0.f, 0.f, 0.f};
                    c = __builtin_amdgcn_mfma_f32_16x16x32_f16(kf0, qf[u][0], c, 0, 0, 0);
                    c = __builtin_amdgcn_mfma_f32_16x16x32_f16(kf1, qf[u][1], c, 0, 0, 0);
                    s[u][nt] = c;
                }
            }
            __builtin_amdgcn_s_setprio(0);

            h4 pf[2][4];
#pragma unroll
            for (int u = 0; u < 2; u++) {
                const int qrow = qbase + u * 16 + l16;
                if (kt * 64 + 63 > qbase + u * 16) {   // causal mask needed
#pragma unroll
                    for (int nt = 0; nt < 4; nt++)
#pragma unroll
                        for (int reg = 0; reg < 4; reg++) {
                            int sg = kt * 64 + nt * 16 + quad * 4 + reg;
                            if (sg > qrow) s[u][nt][reg] = MASKV;
                        }
                }
                float mx = s[u][0][0];
#pragma unroll
                for (int nt = 0; nt < 4; nt++)
#pragma unroll
                    for (int reg = 0; reg < 4; reg++) mx = fmaxf(mx, s[u][nt][reg]);
                mx = fmaxf(mx, __shfl_xor(mx, 16));
                mx = fmaxf(mx, __shfl_xor(mx, 32));
                // T13 defer-max: wave-uniform vote; skip m-update + rescale when the
                // tile max doesn't exceed running max by >8 (log2 domain, P <= 2^8).
                if (!__all(mx <= m[u] + 8.0f)) {
                    float mnew = fmaxf(m[u], mx);
                    float alpha = EXP2(m[u] - mnew);
                    m[u] = mnew;
                    l[u] *= alpha;
#pragma unroll
                    for (int pt = 0; pt < 4; pt++)
#pragma unroll
                        for (int reg = 0; reg < 4; reg++) o[u * 4 + pt][reg] *= alpha;
                }
                float rs = 0.f;
#pragma unroll
                for (int nt = 0; nt < 4; nt++) {
                    h4 ph;
#pragma unroll
                    for (int reg = 0; reg < 4; reg++) {
                        float p = EXP2(s[u][nt][reg] - m[u]);
                        rs += p;
                        ph[reg] = (_Float16)p;
                    }
                    pf[u][nt] = ph;
                }
                rs += __shfl_xor(rs, 16);
                rs += __shfl_xor(rs, 32);
                l[u] += rs;
            }

            // O^T += V^T P^T ; vf shared across strips
            __builtin_amdgcn_s_setprio(1);
#pragma unroll
            for (int pt = 0; pt < 4; pt++)
#pragma unroll
                for (int nt = 0; nt < 4; nt++) {
                    h4 vf = *(const h4*)&Vt[buf][pt * 16 + l16][nt * 16 + quad * 4];
                    o[pt]     = __builtin_amdgcn_mfma_f32_16x16x16f16(vf, pf[0][nt], o[pt], 0, 0, 0);
                    o[4 + pt] = __builtin_amdgcn_mfma_f32_16x16x16f16(vf, pf[1][nt], o[4 + pt], 0, 0, 0);
                }
            __builtin_amdgcn_s_setprio(0);
        }
    }

    if (direct) {
#pragma unroll
        for (int u = 0; u < 2; u++) {
            float linv = 1.0f / l[u];
            int trow = qt2 * 128 + w * 32 + u * 16 + l16;
#pragma unroll
            for (int pt = 0; pt < 4; pt++)
#pragma unroll
                for (int reg = 0; reg < 4; reg++)
                    out[base + (size_t)trow * 64 + pt * 16 + quad * 4 + reg] =
                        o[u * 4 + pt][reg] * linv;
        }
    } else {
        // stage O^T -> LDS -> coalesced h8 stores
        __syncthreads();                       // all waves done reading Ks/Vt
        _Float16* St = &Ks[0][0][0];           // 128 x 72 halfs (exactly 9216)
#pragma unroll
        for (int u = 0; u < 2; u++) {
            int r = w * 32 + u * 16 + l16;
#pragma unroll
            for (int pt = 0; pt < 4; pt++) {
                h4 ph;
#pragma unroll
                for (int reg = 0; reg < 4; reg++) ph[reg] = (_Float16)o[u * 4 + pt][reg];
                *(h4*)&St[r * 72 + pt * 16 + quad * 4] = ph;
            }
            if (quad == 0) ml[(size_t)cid * 128 + r] = make_float2(m[u], l[u]);
        }
        __syncthreads();
        _Float16* op = Opart + (size_t)cid * 8192;   // [128][64] f16
        const int r = tid >> 1, c0 = (tid & 1) * 32;
#pragma unroll
        for (int j = 0; j < 4; j++)
            *(h8*)(op + r * 64 + c0 + 8 * j) = *(const h8*)&St[r * 72 + c0 + 8 * j];
    }
}

// ---------------- kernel 3: merge split-K partials; grid 1024 (16-row groups)
__global__ __launch_bounds__(256) void combine_kernel(
    const _Float16* __restrict__ Opart, const float2* __restrict__ ml,
    float* __restrict__ out, int lgC, int NC1)
{
    const int C = 1 << lgC;
    const int task = blockIdx.x;                  // b(2b) | tile(5b) | rg(3b)
    const int b = task >> 8, tile = (task >> 3) & 31, rg = task & 7;
    int pref = 0;
    for (int i = 0; i < tile; i++) pref += (2 * i + 2 + C - 1) >> lgC;
    const int cbase = b * NC1 + pref;
    const int nch = (2 * tile + 2 + C - 1) >> lgC;

    const int r = rg * 16 + (threadIdx.x >> 4);   // local row in [0,128)
    const int c0 = (threadIdx.x & 15) * 4;

    float M = MINIT;
    for (int i = 0; i < nch; i++) M = fmaxf(M, ml[(size_t)(cbase + i) * 128 + r].x);
    float L = 0.f, acc[4] = {0.f, 0.f, 0.f, 0.f};
    for (int i = 0; i < nch; i++) {
        float2 v = ml[(size_t)(cbase + i) * 128 + r];
        float sc = EXP2(v.x - M);
        L += sc * v.y;
        h4 x4 = *(const h4*)(Opart + (size_t)(cbase + i) * 8192 + (size_t)r * 64 + c0);
#pragma unroll
        for (int t = 0; t < 4; t++) acc[t] += sc * (float)x4[t];
    }
    float inv = 1.0f / L;
    float4 res = { acc[0]*inv, acc[1]*inv, acc[2]*inv, acc[3]*inv };
    *(float4*)(out + ((size_t)b * T_ + tile * 128 + r) * 64 + c0) = res;
}

extern "C" void kernel_launch(void* const* d_in, const int* in_sizes, int n_in,
                              void* d_out, int out_size, void* d_ws, size_t ws_size,
                              hipStream_t stream) {
    const float* x    = (const float*)d_in[0];
    const float* W    = (const float*)d_in[1];
    const float* bias = (const float*)d_in[2];
    float* out = (float*)d_out;
    char* ws = (char*)d_ws;
    _Float16* qh = (_Float16*)(ws);
    _Float16* kh = (_Float16*)(ws + (size_t)2 * 1024 * 1024);
    _Float16* vh = (_Float16*)(ws + (size_t)4 * 1024 * 1024);
    _Float16* Wt = (_Float16*)(ws + (size_t)6 * 1024 * 1024);
    const size_t pbase = (size_t)8 * 1024 * 1024;

    // R7: prefer C=8 (fewer chunks -> less partial traffic + per-chunk overhead);
    // fall back to larger C only if ws can't fit the partials.
    int lgC = -1, nc1 = 32;
    for (int lg = 3; lg <= 6; lg++) {
        int C = 1 << lg, n1 = 0;
        for (int i = 0; i < 32; i++) n1 += (2 * i + 2 + C - 1) >> lg;
        size_t need = pbase + (size_t)4 * n1 * (8192 * 2 + 128 * 8);
        if (need <= ws_size) { lgC = lg; nc1 = n1; break; }
    }
    int direct = (lgC < 0) ? 1 : 0;
    if (direct) { lgC = 6; nc1 = 32; }
    _Float16* Opart = (_Float16*)(ws + pbase);
    float2*   mlp   = (float2*)(ws + pbase + (size_t)4 * nc1 * 8192 * 2);

    const int total = 4 * nc1;
    const int q8 = (total + 7) / 8;

    wt_kernel<<<64, 256, 0, stream>>>(W, Wt);
    proj_kernel<<<512, 256, 0, stream>>>(x, Wt, bias, qh, kh, vh);
    attn_kernel<<<8 * q8, 256, 0, stream>>>(qh, kh, vh, out, Opart, mlp,
                                            lgC, nc1, direct, q8, total);
    if (!direct)
        combine_kernel<<<1024, 256, 0, stream>>>(Opart, mlp, out, lgC, nc1);
}